// Round 3
// baseline (656.846 us; speedup 1.0000x reference)
//
#include <hip/hip_runtime.h>
#include <math.h>

#define N_CODES 4096
#define N_EDGES 8192
#define EMB     128
#define NHEAD   4
#define NNZ     65536
#define K_TOP   6553            // int(0.1 * 65536)
#define S_TOTAL 33554432        // 4096 * 8192
#define NBINS   8192            // 32 KB LDS histogram
#define NREP    16              // global hist replicas (atomic contention /16)
#define CAP2    131072          // candidate cap (pool ~42k at 12-bin slack)
#define SLACK_BINS 12           // 2.93e-3 screening slack >> fp16 round + GEMM noise
#define TIE_CAP 1024

typedef _Float16 f16_t;
typedef __attribute__((ext_vector_type(8))) _Float16 f16x8;
typedef __attribute__((ext_vector_type(4))) float f32x4;

// ---------------- threefry2x32, JAX partitionable scheme, 32-bit path ----------------
__device__ __forceinline__ unsigned rotl32(unsigned v, int r) {
  return (v << r) | (v >> (32 - r));
}

__device__ float jax_u42(unsigned pos) {
  const unsigned ks0 = 0u, ks1 = 42u, ks2 = 0x1BD11BDAu ^ 0u ^ 42u;
  unsigned x0 = 0u  + ks0;
  unsigned x1 = pos + ks1;
#define TFR(r) { x0 += x1; x1 = rotl32(x1, (r)); x1 ^= x0; }
  TFR(13) TFR(15) TFR(26) TFR(6)   x0 += ks1; x1 += ks2 + 1u;
  TFR(17) TFR(29) TFR(16) TFR(24)  x0 += ks2; x1 += ks0 + 2u;
  TFR(13) TFR(15) TFR(26) TFR(6)   x0 += ks0; x1 += ks1 + 3u;
  TFR(17) TFR(29) TFR(16) TFR(24)  x0 += ks1; x1 += ks2 + 4u;
  TFR(13) TFR(15) TFR(26) TFR(6)   x0 += ks2; x1 += ks0 + 5u;
#undef TFR
  unsigned bits = x0 ^ x1;
  unsigned fb = (bits >> 9) | 0x3f800000u;
  float f = __uint_as_float(fb) - 1.0f;
  const float minv = 1e-6f;
  const float maxv = (float)(1.0 - 1e-6);
  float u = f * (maxv - minv) + minv;
  return fmaxf(minv, u);
}

__device__ float mask_val(float p, unsigned pos) {
  float u = jax_u42(pos);
  float l = (logf(p) - log1pf(-p) + logf(u) - log1pf(-u)) * 2.0f; // /TEMP, TEMP=0.5
  return 1.0f / (1.0f + expf(-l));
}

// f64 -> u64 monotone key (larger double <=> larger key)
__device__ __forceinline__ unsigned long long f64key(double v) {
  long long b = __double_as_longlong(v);
  return (b < 0) ? ~(unsigned long long)b
                 : ((unsigned long long)b | 0x8000000000000000ULL);
}

// ---------------- K1: per-edge counts ----------------
__global__ void count_k(const int* __restrict__ E, int* __restrict__ cnt) {
  int i = blockIdx.x * blockDim.x + threadIdx.x;
  if (i < NNZ) atomicAdd(&cnt[E[i]], 1);
}

// ---------------- K2: exclusive scan of 8192 counts ----------------
__global__ __launch_bounds__(1024) void scan_k(const int* __restrict__ cnt,
                                               int* __restrict__ offs) {
  __shared__ int part[1024];
  int t = threadIdx.x;
  int local[8]; int s = 0;
  for (int j = 0; j < 8; ++j) { local[j] = cnt[t * 8 + j]; s += local[j]; }
  part[t] = s; __syncthreads();
  int v = s;
  for (int o = 1; o < 1024; o <<= 1) {
    int add = (t >= o) ? part[t - o] : 0;
    __syncthreads();
    v += add; part[t] = v;
    __syncthreads();
  }
  int base = v - s;
  for (int j = 0; j < 8; ++j) { offs[t * 8 + j] = base; base += local[j]; }
}

// ---------------- K3: bucket scatter (CSR) ----------------
__global__ void scatter_k(const int* __restrict__ E, const int* __restrict__ offs,
                          int* __restrict__ cursor, int* __restrict__ bucket) {
  int i = blockIdx.x * blockDim.x + threadIdx.x;
  if (i < NNZ) {
    int e = E[i];
    int p = atomicAdd(&cursor[e], 1);
    bucket[offs[e] + p] = i;
  }
}

// ---------------- K4: sort CSR lists, fused-normalized fp16 B operand ----------------
// B16[m][h*128+d] = eX[m][d] * W[h][d]^2 * (1/max(||eX_m o W_h||,1e-6))
__global__ __launch_bounds__(128) void edge_k(const float* __restrict__ X,
                                              const int* __restrict__ V,
                                              const int* __restrict__ cnt,
                                              const int* __restrict__ offs,
                                              int* __restrict__ bucket,
                                              const float* __restrict__ W,
                                              f16_t* __restrict__ B16) {
  __shared__ int lst[512];
  __shared__ float red[2];
  int m = blockIdx.x, t = threadIdx.x;
  int deg = cnt[m], off = offs[m];
  int n = min(deg, 512);
  for (int j = t; j < n; j += 128) lst[j] = bucket[off + j];
  __syncthreads();
  if (t == 0 && n > 1) {             // ascending-index order == np.add.at order
    for (int a = 1; a < n; ++a) {
      int key = lst[a]; int b = a - 1;
      while (b >= 0 && lst[b] > key) { lst[b + 1] = lst[b]; --b; }
      lst[b + 1] = key;
    }
  }
  __syncthreads();
  for (int j = t; j < n; j += 128) bucket[off + j] = lst[j];  // sorted CSR for rescore
  float s = 0.f;
  for (int j = 0; j < n; ++j) s += X[(size_t)V[lst[j]] * EMB + t];
  float eXd = s / fmaxf((float)deg, 1.0f);
  int lane = t & 63, wv = t >> 6;
  for (int h = 0; h < NHEAD; ++h) {
    float wd = W[h * EMB + t];
    float val = eXd * wd;
    float ss = val * val;
    for (int o = 32; o > 0; o >>= 1) ss += __shfl_down(ss, o, 64);
    if (lane == 0) red[wv] = ss;
    __syncthreads();
    float nh = 1.0f / fmaxf(sqrtf(red[0] + red[1]), 1e-6f);
    B16[(size_t)m * (NHEAD * EMB) + h * EMB + t] = (f16_t)(eXd * wd * wd * nh);
    __syncthreads();
  }
}

// ---------------- K5: fused-normalized fp16 A operand ----------------
// A16[n][h*128+d] = X[n][d] * (1/max(||X_n o W_h||,1e-6))   (W^2 folded into B side)
__global__ __launch_bounds__(128) void node_k(const float* __restrict__ X,
                                              const float* __restrict__ W,
                                              f16_t* __restrict__ A16) {
  __shared__ float red[2];
  int nid = blockIdx.x, t = threadIdx.x;
  float xd = X[(size_t)nid * EMB + t];
  int lane = t & 63, wv = t >> 6;
  for (int h = 0; h < NHEAD; ++h) {
    float val = xd * W[h * EMB + t];
    float ss = val * val;
    for (int o = 32; o > 0; o >>= 1) ss += __shfl_down(ss, o, 64);
    if (lane == 0) red[wv] = ss;
    __syncthreads();
    float nh = 1.0f / fmaxf(sqrtf(red[0] + red[1]), 1e-6f);
    A16[(size_t)nid * (NHEAD * EMB) + h * EMB + t] = (f16_t)(xd * nh);
    __syncthreads();
  }
}

// ---------------- K6: single fp16 MFMA GEMM pass — S16 write + histogram ----------------
// Register-direct pipeline: NO LDS operand staging, NO barriers in the K-loop.
// Each wave owns a 64x64 output tile; fragments loaded straight to VGPRs
// (global_load_dwordx4, per-lane addr = row*512 + fg*8 — the native 16x16x32 A/B
// fragment layout), ping-pong double-buffered with STATIC register names (rule #20).
// The compiler emits counted vmcnt for register loads (G7) — the structural
// vmcnt(0)-drain that capped the LDS version at MfmaUtil 11% is gone.
// Epilogue: bin the fp16-ROUNDED value (identical to what collect16 compares) into a
// 32KB LDS hist, merge to 1 of 16 global replicas; store S16 (fp16 scores).
__global__ __launch_bounds__(256, 2) void gemm_k(const f16_t* __restrict__ A16,
                                                 const f16_t* __restrict__ B16,
                                                 unsigned short* __restrict__ S16,
                                                 unsigned* __restrict__ ghist) {
  __shared__ unsigned hh[NBINS];           // 32 KB
  const int tid  = threadIdx.x;
  const int lane = tid & 63;
  const int wv   = tid >> 6;
  const int m0   = blockIdx.x * 128;       // edge cols
  const int n0   = blockIdx.y * 128;       // node rows
  const int wr   = (wv >> 1) * 64;         // wave row offset
  const int wc   = (wv & 1) * 64;          // wave col offset
  const int frow = lane & 15;
  const int fg   = lane >> 4;

  for (int i = tid; i < NBINS; i += 256) hh[i] = 0;
  __syncthreads();

  const f16_t* pA = A16 + ((size_t)(n0 + wr + frow) << 9) + fg * 8;
  const f16_t* pB = B16 + ((size_t)(m0 + wc + frow) << 9) + fg * 8;

  f32x4 acc[4][4];
#pragma unroll
  for (int i = 0; i < 4; ++i)
#pragma unroll
    for (int j = 0; j < 4; ++j) acc[i][j] = (f32x4){0.f, 0.f, 0.f, 0.f};

  f16x8 a0[4], b0[4], a1[4], b1[4];

#define LOADF(da, db, ks)                                                   \
  _Pragma("unroll") for (int i = 0; i < 4; ++i)                             \
    da[i] = *(const f16x8*)(pA + (size_t)i * (16 * 512) + (ks) * 32);       \
  _Pragma("unroll") for (int j = 0; j < 4; ++j)                             \
    db[j] = *(const f16x8*)(pB + (size_t)j * (16 * 512) + (ks) * 32);

#define MM(aa, bb)                                                          \
  _Pragma("unroll") for (int i = 0; i < 4; ++i)                             \
    _Pragma("unroll") for (int j = 0; j < 4; ++j)                           \
      acc[i][j] = __builtin_amdgcn_mfma_f32_16x16x32_f16(aa[i], bb[j],      \
                                                         acc[i][j], 0, 0, 0);

  LOADF(a0, b0, 0)
#pragma unroll
  for (int t = 0; t < 16; t += 2) {
    LOADF(a1, b1, t + 1)          // prefetch next K-step while computing current
    MM(a0, b0)
    if (t + 2 < 16) { LOADF(a0, b0, t + 2) }
    MM(a1, b1)
  }
#undef LOADF
#undef MM

  // epilogue: fp16-round, store S16, bin the ROUNDED value (bit-identical to collect16)
#pragma unroll
  for (int i = 0; i < 4; ++i)
#pragma unroll
    for (int j = 0; j < 4; ++j)
#pragma unroll
      for (int q = 0; q < 4; ++q) {
        float v = acc[i][j][q] * 0.25f;
        f16_t h = (f16_t)v;
        int row = n0 + wr + i * 16 + fg * 4 + q;  // C/D layout (m89-verified)
        int col = m0 + wc + j * 16 + frow;
        S16[(size_t)row * N_EDGES + col] = __builtin_bit_cast(unsigned short, h);
        float hv = (float)h;
        float bf = fminf(fmaxf((hv + 1.0f) * 4096.0f, 0.0f), (float)(NBINS - 1));
        atomicAdd(&hh[(int)bf], 1u);
      }
  __syncthreads();
  unsigned* gh = ghist + (size_t)(blockIdx.x & (NREP - 1)) * NBINS;
  for (int i = tid; i < NBINS; i += 256) {
    unsigned c = hh[i];
    if (c) atomicAdd(&gh[i], c);
  }
}

// ---------------- K7: mask existing incidences in S16 (fp16 -inf) ----------------
__global__ void maskset16_k(const int* __restrict__ V, const int* __restrict__ E,
                            unsigned short* __restrict__ S16) {
  int i = blockIdx.x * blockDim.x + threadIdx.x;
  if (i < NNZ) S16[(size_t)V[i] * N_EDGES + E[i]] = 0xFC00u;  // -inf
}

// ---------------- K8: histogram correction for existing (V,E) incidences ----------------
// Subtract each member's fp16-rounded screen-score bin (serial f32 dot may differ from
// the MFMA value by an ulp -> +/-1 bin straddle; thresh_k's SIGNED sums absorb it).
__global__ __launch_bounds__(256) void corr_k(const f16_t* __restrict__ A16,
                                              const f16_t* __restrict__ B16,
                                              const int* __restrict__ V,
                                              const int* __restrict__ E,
                                              unsigned* __restrict__ ghist) {
  int wave = threadIdx.x >> 6, lane = threadIdx.x & 63;
  int j = blockIdx.x * 4 + wave;
  if (j >= NNZ) return;
  int n = V[j], m = E[j];
  f16x8 a = *(const f16x8*)(A16 + ((size_t)n << 9) + lane * 8);
  f16x8 b = *(const f16x8*)(B16 + ((size_t)m << 9) + lane * 8);
  float s = 0.f;
#pragma unroll
  for (int c = 0; c < 8; ++c) s += (float)a[c] * (float)b[c];
  for (int o = 32; o > 0; o >>= 1) s += __shfl_down(s, o, 64);
  if (lane == 0) {
    float hv = (float)(f16_t)(s * 0.25f);
    float bf = fminf(fmaxf((hv + 1.0f) * 4096.0f, 0.0f), (float)(NBINS - 1));
    atomicAdd(&ghist[(size_t)(j & (NREP - 1)) * NBINS + (int)bf], (unsigned)-1);
  }
}

// ---------------- K9: screening threshold, SLACK_BINS below the k-th bin ----------------
// SIGNED arithmetic: corrected bins can be transiently negative (straddlers).
__global__ __launch_bounds__(1024) void thresh_k(const unsigned* __restrict__ hist,
                                                 float* __restrict__ T_lo) {
  __shared__ int suff[1024];
  int t = threadIdx.x;
  const int G = NBINS / 1024;
  int b0 = t * G;
  int s = 0;
  for (int j = 0; j < G; ++j) {
    unsigned tb = 0;
    for (int r = 0; r < NREP; ++r) tb += hist[(size_t)r * NBINS + b0 + j];
    s += (int)tb;
  }
  int v = s;
  suff[t] = v; __syncthreads();
  for (int o = 1; o < 1024; o <<= 1) {
    int add = (t + o < 1024) ? suff[t + o] : 0;
    __syncthreads();
    v += add; suff[t] = v;
    __syncthreads();
  }
  int above = (t < 1023) ? suff[t + 1] : 0;
  if (above < K_TOP && suff[t] >= K_TOP) {
    int running = above;
    int B = b0;
    for (int b = b0 + G - 1; b >= b0; --b) {
      unsigned tb = 0;
      for (int r = 0; r < NREP; ++r) tb += hist[(size_t)r * NBINS + b];
      running += (int)tb;
      if (running >= K_TOP) { B = b; break; }
    }
    B = max(B, SLACK_BINS);
    *T_lo = (float)(B - SLACK_BINS) * (1.0f / 4096.0f) - 1.0f;
  }
}

// ---------------- K10: compact candidates from S16 (masked entries are -inf) ----------------
__global__ __launch_bounds__(256) void collect16_k(const f16x8* __restrict__ S8,
                                                   const float* __restrict__ T_lo_p,
                                                   unsigned* __restrict__ counter,
                                                   int* __restrict__ ci) {
  float T = *T_lo_p;
  int stride = gridDim.x * blockDim.x;
  for (int i = blockIdx.x * blockDim.x + threadIdx.x; i < S_TOTAL / 8; i += stride) {
    f16x8 h = S8[i];
#pragma unroll
    for (int c = 0; c < 8; ++c) {
      if ((float)h[c] >= T) {
        unsigned j = atomicAdd(counter, 1u);
        if (j < CAP2) ci[j] = i * 8 + c;
      }
    }
  }
}

// ---------------- K11: FULL f64 rescore -> monotone u64 key (1 wave / candidate) ----------------
__global__ __launch_bounds__(256) void rescore_k(const float* __restrict__ X,
                                                 const float* __restrict__ W,
                                                 const int* __restrict__ V,
                                                 const int* __restrict__ cnt,
                                                 const int* __restrict__ offs,
                                                 const int* __restrict__ bucket,
                                                 const int* __restrict__ ci,
                                                 const unsigned* __restrict__ counter,
                                                 unsigned long long* __restrict__ ckey) {
  int C = (int)min(*counter, (unsigned)CAP2);
  int wave = threadIdx.x >> 6, lane = threadIdx.x & 63;
  int j = blockIdx.x * 4 + wave;
  if (j >= C) return;
  int pos = ci[j];
  int n = pos >> 13;
  int m = pos & 8191;
  int deg = cnt[m], off = offs[m];
  int nmem = min(deg, 512);
  double e0 = 0.0, e1 = 0.0;
  for (int q = 0; q < nmem; ++q) {
    const float* xv = X + (size_t)V[bucket[off + q]] * EMB;
    e0 += (double)xv[lane];
    e1 += (double)xv[lane + 64];
  }
  double dd = fmax((double)deg, 1.0);
  e0 /= dd; e1 /= dd;
  const float* xr = X + (size_t)n * EMB;
  double x0 = (double)xr[lane], x1 = (double)xr[lane + 64];
  double s = 0.0;
  for (int h = 0; h < NHEAD; ++h) {
    const float* wr = W + h * EMB;
    double w0 = (double)wr[lane], w1 = (double)wr[lane + 64];
    double xw0 = x0 * w0, xw1 = x1 * w1;
    double ew0 = e0 * w0, ew1 = e1 * w1;
    double an = xw0 * xw0 + xw1 * xw1;
    double ae = ew0 * ew0 + ew1 * ew1;
    double dt = xw0 * ew0 + xw1 * ew1;
    for (int o = 32; o > 0; o >>= 1) {
      an += __shfl_down(an, o, 64);
      ae += __shfl_down(ae, o, 64);
      dt += __shfl_down(dt, o, 64);
    }
    if (lane == 0) {
      double Nn = fmax(sqrt(an), 1e-6);
      double Ne = fmax(sqrt(ae), 1e-6);
      s += dt / (Nn * Ne);
    }
  }
  if (lane == 0) ckey[j] = f64key(s * 0.25);
}

// ---------------- K12: exact k-th largest key via 8-level byte radix select ----------------
__global__ __launch_bounds__(1024) void kth_k(const unsigned long long* __restrict__ keys,
                                              const unsigned* __restrict__ counter,
                                              unsigned long long* __restrict__ thr) {
  __shared__ unsigned hist[256];
  __shared__ unsigned long long s_prefix;
  __shared__ unsigned s_kleft, s_cgreat;
  int C = (int)min(*counter, (unsigned)CAP2);
  if (threadIdx.x == 0) { s_prefix = 0ULL; s_kleft = K_TOP; s_cgreat = 0u; }
  __syncthreads();
  for (int level = 7; level >= 0; --level) {
    for (int i = threadIdx.x; i < 256; i += 1024) hist[i] = 0;
    __syncthreads();
    unsigned long long prefix = s_prefix;
    unsigned long long pmask = (level == 7) ? 0ULL : (~0ULL << ((level + 1) * 8));
    for (int i = threadIdx.x; i < C; i += 1024) {
      unsigned long long k = keys[i];
      if ((k & pmask) == prefix)
        atomicAdd(&hist[(unsigned)((k >> (level * 8)) & 0xFF)], 1u);
    }
    __syncthreads();
    if (threadIdx.x == 0) {
      unsigned cum = 0; int b = 0;
      for (int i = 255; i >= 0; --i) {
        if (cum + hist[i] >= s_kleft) { b = i; break; }
        cum += hist[i];
      }
      s_prefix |= ((unsigned long long)b << (level * 8));
      s_kleft  -= cum;
      s_cgreat += cum;
    }
    __syncthreads();
  }
  if (threadIdx.x == 0) { thr[0] = s_prefix; thr[1] = (unsigned long long)s_cgreat; }
}

// ---------------- K13: write masks for key > thr; gather ties at key == thr ----------------
__global__ void write_k(const unsigned long long* __restrict__ keys,
                        const int* __restrict__ ci,
                        const unsigned* __restrict__ counter,
                        const unsigned long long* __restrict__ thr,
                        const float* __restrict__ P, float* __restrict__ out,
                        int* __restrict__ tiebuf, unsigned* __restrict__ tiecnt) {
  int C = (int)min(*counter, (unsigned)CAP2);
  int j = blockIdx.x * blockDim.x + threadIdx.x;
  if (j >= C) return;
  unsigned long long k = keys[j];
  unsigned long long t = thr[0];
  if (k > t) {
    unsigned pos = (unsigned)ci[j];
    out[pos] = mask_val(P[pos], pos);
  } else if (k == t) {
    unsigned q = atomicAdd(tiecnt, 1u);
    if (q < TIE_CAP) tiebuf[q] = ci[j];
  }
}

// ---------------- K14: fill remaining slots from ties, ascending index ----------------
__global__ __launch_bounds__(256) void tiefin_k(const int* __restrict__ tiebuf,
                                                const unsigned* __restrict__ tiecnt,
                                                const unsigned long long* __restrict__ thr,
                                                const float* __restrict__ P,
                                                float* __restrict__ out) {
  __shared__ int idx[TIE_CAP];
  int T = (int)min(*tiecnt, (unsigned)TIE_CAP);
  int need = K_TOP - (int)thr[1];
  if (need <= 0 || T == 0) return;       // uniform exit
  for (int i = threadIdx.x; i < T; i += 256) idx[i] = tiebuf[i];
  __syncthreads();
  if (threadIdx.x == 0 && T > 1) {       // ascending flat index (top_k stable order)
    for (int a = 1; a < T; ++a) {
      int key = idx[a]; int b = a - 1;
      while (b >= 0 && idx[b] > key) { idx[b + 1] = idx[b]; --b; }
      idx[b + 1] = key;
    }
  }
  __syncthreads();
  int m = min(need, T);
  for (int i = threadIdx.x; i < m; i += 256) {
    unsigned pos = (unsigned)idx[i];
    out[pos] = mask_val(P[pos], pos);
  }
}

// ---------------- K15: H positions (the (V,E) pairs) ----------------
__global__ void scatterH_k(const int* __restrict__ V, const int* __restrict__ E,
                           const float* __restrict__ P, float* __restrict__ out) {
  int i = blockIdx.x * blockDim.x + threadIdx.x;
  if (i >= NNZ) return;
  unsigned pos = (unsigned)V[i] * (unsigned)N_EDGES + (unsigned)E[i];
  out[pos] = mask_val(P[pos], pos);
}

extern "C" void kernel_launch(void* const* d_in, const int* in_sizes, int n_in,
                              void* d_out, int out_size, void* d_ws, size_t ws_size,
                              hipStream_t stream) {
  const float* X = (const float*)d_in[0];
  // d_in[1] = H (unused: nonzeros are exactly the (V,E) pairs)
  const int*   V = (const int*)d_in[2];
  const int*   E = (const int*)d_in[3];
  const float* P = (const float*)d_in[4];
  const float* W = (const float*)d_in[5];
  float* OUT = (float*)d_out;

  // S16 (fp16 scores, 64 MB) lives in the UPPER HALF of d_out; consumed by
  // maskset16/collect16, then the full d_out is memset before the final writes.
  unsigned short* S16 = (unsigned short*)((char*)d_out + (size_t)S_TOTAL * 2);

  // ws layout — ~14.5 MB. ghist ALIASES cand_idx (lifetimes disjoint:
  // ghist dies at thresh_k; cand_idx born at collect16_k).
  char* w = (char*)d_ws;
  int*      cnt      = (int*)(w + 0);            // 32 KB
  int*      offs     = (int*)(w + 32768);        // 32 KB
  int*      cursor   = (int*)(w + 65536);        // 32 KB
  int*      bucket   = (int*)(w + 98304);        // 256 KB -> 360448
  unsigned* counter  = (unsigned*)(w + 360448);  // 4 B
  float*    T_lo     = (float*)(w + 360452);     // 4 B
  unsigned* tiecnt   = (unsigned*)(w + 360456);  // 4 B
  unsigned long long* thr = (unsigned long long*)(w + 360464); // 16 B
  int*      cand_idx = (int*)(w + 360704);       // 512 KB -> 884992
  unsigned* ghist    = (unsigned*)(w + 360704);  // 512 KB alias (16 x 8192 x 4 B)
  unsigned long long* cand_key = (unsigned long long*)(w + 884992); // 1 MB -> 1933568
  int*      tiebuf   = (int*)(w + 1933568);      // 4 KB   -> 1937664
  f16_t*    A16      = (f16_t*)(w + 1937664);    // 4 MB   -> 6131968 (16B aligned)
  f16_t*    B16      = (f16_t*)(w + 6131968);    // 8 MB   -> 14520576 (16B aligned)

  hipMemsetAsync(cnt,     0, 32768, stream);
  hipMemsetAsync(cursor,  0, 32768, stream);
  hipMemsetAsync((void*)(w + 360448), 0, 64, stream);   // counter, T_lo, tiecnt, thr
  hipMemsetAsync(ghist,   0, (size_t)NREP * NBINS * 4, stream);

  count_k     <<<NNZ / 256, 256, 0, stream>>>(E, cnt);
  scan_k      <<<1, 1024, 0, stream>>>(cnt, offs);
  scatter_k   <<<NNZ / 256, 256, 0, stream>>>(E, offs, cursor, bucket);
  edge_k      <<<N_EDGES, 128, 0, stream>>>(X, V, cnt, offs, bucket, W, B16);
  node_k      <<<N_CODES, 128, 0, stream>>>(X, W, A16);
  gemm_k      <<<dim3(N_EDGES / 128, N_CODES / 128), 256, 0, stream>>>(A16, B16, S16, ghist);
  maskset16_k <<<NNZ / 256, 256, 0, stream>>>(V, E, S16);
  corr_k      <<<NNZ / 4, 256, 0, stream>>>(A16, B16, V, E, ghist);
  thresh_k    <<<1, 1024, 0, stream>>>(ghist, T_lo);
  collect16_k <<<2048, 256, 0, stream>>>((const f16x8*)S16, T_lo, counter, cand_idx);
  rescore_k   <<<CAP2 / 4, 256, 0, stream>>>(X, W, V, cnt, offs, bucket,
                                             cand_idx, counter, cand_key);
  kth_k       <<<1, 1024, 0, stream>>>(cand_key, counter, thr);
  hipMemsetAsync(d_out, 0, (size_t)S_TOTAL * 4, stream);  // after S16 consumed
  write_k     <<<CAP2 / 256, 256, 0, stream>>>(cand_key, cand_idx, counter, thr,
                                               P, OUT, tiebuf, tiecnt);
  tiefin_k    <<<1, 256, 0, stream>>>(tiebuf, tiecnt, thr, P, OUT);
  scatterH_k  <<<NNZ / 256, 256, 0, stream>>>(V, E, P, OUT);
}

// Round 4
// 584.524 us; speedup vs baseline: 1.1237x; 1.1237x over previous
//
#include <hip/hip_runtime.h>
#include <math.h>

#define N_CODES 4096
#define N_EDGES 8192
#define EMB     128
#define NHEAD   4
#define NNZ     65536
#define K_TOP   6553            // int(0.1 * 65536)
#define S_TOTAL 33554432        // 4096 * 8192
#define NBINS   8192            // 32 KB LDS histogram
#define NREP    16              // global hist replicas (atomic contention /16)
#define CAP2    131072          // candidate cap (pool ~42k at 12-bin slack)
#define SLACK_BINS 12           // 2.93e-3 screening slack >> fp16 round + GEMM noise
#define TIE_CAP 1024

typedef _Float16 f16_t;
typedef __attribute__((ext_vector_type(8))) _Float16 f16x8;
typedef __attribute__((ext_vector_type(4))) float f32x4;

// ---------------- threefry2x32, JAX partitionable scheme, 32-bit path ----------------
__device__ __forceinline__ unsigned rotl32(unsigned v, int r) {
  return (v << r) | (v >> (32 - r));
}

__device__ float jax_u42(unsigned pos) {
  const unsigned ks0 = 0u, ks1 = 42u, ks2 = 0x1BD11BDAu ^ 0u ^ 42u;
  unsigned x0 = 0u  + ks0;
  unsigned x1 = pos + ks1;
#define TFR(r) { x0 += x1; x1 = rotl32(x1, (r)); x1 ^= x0; }
  TFR(13) TFR(15) TFR(26) TFR(6)   x0 += ks1; x1 += ks2 + 1u;
  TFR(17) TFR(29) TFR(16) TFR(24)  x0 += ks2; x1 += ks0 + 2u;
  TFR(13) TFR(15) TFR(26) TFR(6)   x0 += ks0; x1 += ks1 + 3u;
  TFR(17) TFR(29) TFR(16) TFR(24)  x0 += ks1; x1 += ks2 + 4u;
  TFR(13) TFR(15) TFR(26) TFR(6)   x0 += ks2; x1 += ks0 + 5u;
#undef TFR
  unsigned bits = x0 ^ x1;
  unsigned fb = (bits >> 9) | 0x3f800000u;
  float f = __uint_as_float(fb) - 1.0f;
  const float minv = 1e-6f;
  const float maxv = (float)(1.0 - 1e-6);
  float u = f * (maxv - minv) + minv;
  return fmaxf(minv, u);
}

__device__ float mask_val(float p, unsigned pos) {
  float u = jax_u42(pos);
  float l = (logf(p) - log1pf(-p) + logf(u) - log1pf(-u)) * 2.0f; // /TEMP, TEMP=0.5
  return 1.0f / (1.0f + expf(-l));
}

// f64 -> u64 monotone key (larger double <=> larger key)
__device__ __forceinline__ unsigned long long f64key(double v) {
  long long b = __double_as_longlong(v);
  return (b < 0) ? ~(unsigned long long)b
                 : ((unsigned long long)b | 0x8000000000000000ULL);
}

// ---------------- K1: per-edge counts ----------------
__global__ void count_k(const int* __restrict__ E, int* __restrict__ cnt) {
  int i = blockIdx.x * blockDim.x + threadIdx.x;
  if (i < NNZ) atomicAdd(&cnt[E[i]], 1);
}

// ---------------- K2: exclusive scan of 8192 counts ----------------
__global__ __launch_bounds__(1024) void scan_k(const int* __restrict__ cnt,
                                               int* __restrict__ offs) {
  __shared__ int part[1024];
  int t = threadIdx.x;
  int local[8]; int s = 0;
  for (int j = 0; j < 8; ++j) { local[j] = cnt[t * 8 + j]; s += local[j]; }
  part[t] = s; __syncthreads();
  int v = s;
  for (int o = 1; o < 1024; o <<= 1) {
    int add = (t >= o) ? part[t - o] : 0;
    __syncthreads();
    v += add; part[t] = v;
    __syncthreads();
  }
  int base = v - s;
  for (int j = 0; j < 8; ++j) { offs[t * 8 + j] = base; base += local[j]; }
}

// ---------------- K3: bucket scatter (CSR) ----------------
__global__ void scatter_k(const int* __restrict__ E, const int* __restrict__ offs,
                          int* __restrict__ cursor, int* __restrict__ bucket) {
  int i = blockIdx.x * blockDim.x + threadIdx.x;
  if (i < NNZ) {
    int e = E[i];
    int p = atomicAdd(&cursor[e], 1);
    bucket[offs[e] + p] = i;
  }
}

// ---------------- K4: sort CSR lists, fused-normalized fp16 B operand ----------------
// B16[m][h*128+d] = eX[m][d] * W[h][d]^2 * (1/max(||eX_m o W_h||,1e-6))
__global__ __launch_bounds__(128) void edge_k(const float* __restrict__ X,
                                              const int* __restrict__ V,
                                              const int* __restrict__ cnt,
                                              const int* __restrict__ offs,
                                              int* __restrict__ bucket,
                                              const float* __restrict__ W,
                                              f16_t* __restrict__ B16) {
  __shared__ int lst[512];
  __shared__ float red[2];
  int m = blockIdx.x, t = threadIdx.x;
  int deg = cnt[m], off = offs[m];
  int n = min(deg, 512);
  for (int j = t; j < n; j += 128) lst[j] = bucket[off + j];
  __syncthreads();
  if (t == 0 && n > 1) {             // ascending-index order == np.add.at order
    for (int a = 1; a < n; ++a) {
      int key = lst[a]; int b = a - 1;
      while (b >= 0 && lst[b] > key) { lst[b + 1] = lst[b]; --b; }
      lst[b + 1] = key;
    }
  }
  __syncthreads();
  for (int j = t; j < n; j += 128) bucket[off + j] = lst[j];  // sorted CSR for rescore
  float s = 0.f;
  for (int j = 0; j < n; ++j) s += X[(size_t)V[lst[j]] * EMB + t];
  float eXd = s / fmaxf((float)deg, 1.0f);
  int lane = t & 63, wv = t >> 6;
  for (int h = 0; h < NHEAD; ++h) {
    float wd = W[h * EMB + t];
    float val = eXd * wd;
    float ss = val * val;
    for (int o = 32; o > 0; o >>= 1) ss += __shfl_down(ss, o, 64);
    if (lane == 0) red[wv] = ss;
    __syncthreads();
    float nh = 1.0f / fmaxf(sqrtf(red[0] + red[1]), 1e-6f);
    B16[(size_t)m * (NHEAD * EMB) + h * EMB + t] = (f16_t)(eXd * wd * wd * nh);
    __syncthreads();
  }
}

// ---------------- K5: fused-normalized fp16 A operand ----------------
// A16[n][h*128+d] = X[n][d] * (1/max(||X_n o W_h||,1e-6))   (W^2 folded into B side)
__global__ __launch_bounds__(128) void node_k(const float* __restrict__ X,
                                              const float* __restrict__ W,
                                              f16_t* __restrict__ A16) {
  __shared__ float red[2];
  int nid = blockIdx.x, t = threadIdx.x;
  float xd = X[(size_t)nid * EMB + t];
  int lane = t & 63, wv = t >> 6;
  for (int h = 0; h < NHEAD; ++h) {
    float val = xd * W[h * EMB + t];
    float ss = val * val;
    for (int o = 32; o > 0; o >>= 1) ss += __shfl_down(ss, o, 64);
    if (lane == 0) red[wv] = ss;
    __syncthreads();
    float nh = 1.0f / fmaxf(sqrtf(red[0] + red[1]), 1e-6f);
    A16[(size_t)nid * (NHEAD * EMB) + h * EMB + t] = (f16_t)(xd * nh);
    __syncthreads();
  }
}

// ---------------- K6: fp16 MFMA GEMM (R1-proven structure) -> S16 ----------------
// m97 structure: 128x128 tile, 4 waves (2x2 of 64x64), BK=32, 16x16x32 MFMA,
// global_load_lds width=16 staging, source-side XOR swizzle (rule #21: source
// permutation == read permutation, LDS linear). Verified 0 bank conflicts (R2 PMC).
// Only change vs R1: C-write is fp16 (S16) — halves GEMM write traffic.
__global__ __launch_bounds__(256) void gemm_k(const f16_t* __restrict__ A16,
                                              const f16_t* __restrict__ B16,
                                              unsigned short* __restrict__ S16) {
  __shared__ __align__(16) f16_t As[128 * 32];
  __shared__ __align__(16) f16_t Bs[128 * 32];
  const int tid  = threadIdx.x;
  const int lane = tid & 63;
  const int wv   = tid >> 6;
  const int m0   = blockIdx.x * 128;       // edge cols
  const int n0   = blockIdx.y * 128;       // node rows
  const int wr   = (wv >> 1) * 64;
  const int wc   = (wv & 1) * 64;
  const int frow = lane & 15;
  const int fg   = lane >> 4;
  const int sw   = (frow >> 1) & 3;
  const int fo   = ((fg ^ sw) << 3);

  f32x4 acc[4][4];
#pragma unroll
  for (int i = 0; i < 4; ++i)
#pragma unroll
    for (int j = 0; j < 4; ++j) acc[i][j] = (f32x4){0.f, 0.f, 0.f, 0.f};

  for (int k0 = 0; k0 < 512; k0 += 32) {
    __syncthreads();
#pragma unroll
    for (int r = 0; r < 2; ++r) {
      int chunk = r * 256 + wv * 64 + lane;
      int row   = chunk >> 2;
      int cb    = ((chunk & 3) ^ ((chunk >> 3) & 3)) << 3;
      __builtin_amdgcn_global_load_lds(
          (const __attribute__((address_space(1))) void*)
              (A16 + ((size_t)(n0 + row) << 9) + k0 + cb),
          (__attribute__((address_space(3))) void*)
              (As + (size_t)(r * 256 + wv * 64) * 8),
          16, 0, 0);
      __builtin_amdgcn_global_load_lds(
          (const __attribute__((address_space(1))) void*)
              (B16 + ((size_t)(m0 + row) << 9) + k0 + cb),
          (__attribute__((address_space(3))) void*)
              (Bs + (size_t)(r * 256 + wv * 64) * 8),
          16, 0, 0);
    }
    __syncthreads();
    f16x8 a[4], b[4];
#pragma unroll
    for (int i = 0; i < 4; ++i)
      a[i] = *(const f16x8*)(As + (wr + i * 16 + frow) * 32 + fo);
#pragma unroll
    for (int j = 0; j < 4; ++j)
      b[j] = *(const f16x8*)(Bs + (wc + j * 16 + frow) * 32 + fo);
#pragma unroll
    for (int i = 0; i < 4; ++i)
#pragma unroll
      for (int j = 0; j < 4; ++j)
        acc[i][j] = __builtin_amdgcn_mfma_f32_16x16x32_f16(a[i], b[j], acc[i][j], 0, 0, 0);
  }
  // C/D layout (m89-verified): col = lane&15, row = (lane>>4)*4 + q
#pragma unroll
  for (int i = 0; i < 4; ++i)
#pragma unroll
    for (int q = 0; q < 4; ++q) {
      int row = n0 + wr + i * 16 + fg * 4 + q;
      unsigned short* Sr = S16 + (size_t)row * N_EDGES + m0 + wc;
#pragma unroll
      for (int j = 0; j < 4; ++j) {
        f16_t h = (f16_t)(acc[i][j][q] * 0.25f);
        Sr[j * 16 + frow] = __builtin_bit_cast(unsigned short, h);
      }
    }
}

// ---------------- K7: mask existing incidences in S16 (fp16 -inf) ----------------
// Runs BEFORE hist16 (R1 semantics): masked entries land in bin 0, never counted.
__global__ void maskset16_k(const int* __restrict__ V, const int* __restrict__ E,
                            unsigned short* __restrict__ S16) {
  int i = blockIdx.x * blockDim.x + threadIdx.x;
  if (i < NNZ) S16[(size_t)V[i] * N_EDGES + E[i]] = 0xFC00u;  // -inf
}

// ---------------- K8: 8192-bin histogram over S16, x4 MLP-unrolled ----------------
// R1's collect ran at 1.5 TB/s with VALUBusy 1.9% — 1 load in flight per wave
// (latency-bound). 4 stride-spaced independent loads per iter fixes the MLP.
__global__ __launch_bounds__(256) void hist16_k(const f16x8* __restrict__ S8,
                                                unsigned* __restrict__ ghist) {
  __shared__ unsigned hh[NBINS];
  for (int i = threadIdx.x; i < NBINS; i += 256) hh[i] = 0;
  __syncthreads();
  const int stride = gridDim.x * blockDim.x;
  int i = blockIdx.x * blockDim.x + threadIdx.x;
#define BIN8(v)                                                              \
  _Pragma("unroll") for (int c = 0; c < 8; ++c) {                            \
    float bf = fminf(fmaxf(((float)(v)[c] + 1.0f) * 4096.0f, 0.0f),          \
                     (float)(NBINS - 1));                                    \
    atomicAdd(&hh[(int)bf], 1u);                                             \
  }
  for (; i + 3 * stride < S_TOTAL / 8; i += 4 * stride) {
    f16x8 v0 = S8[i];
    f16x8 v1 = S8[i + stride];
    f16x8 v2 = S8[i + 2 * stride];
    f16x8 v3 = S8[i + 3 * stride];
    BIN8(v0) BIN8(v1) BIN8(v2) BIN8(v3)
  }
  for (; i < S_TOTAL / 8; i += stride) { f16x8 v = S8[i]; BIN8(v) }
#undef BIN8
  __syncthreads();
  unsigned* gh = ghist + (size_t)(blockIdx.x & (NREP - 1)) * NBINS;
  for (int i2 = threadIdx.x; i2 < NBINS; i2 += 256) {
    unsigned c = hh[i2];
    if (c) atomicAdd(&gh[i2], c);
  }
}

// ---------------- K9: screening threshold, SLACK_BINS below the k-th bin ----------------
__global__ __launch_bounds__(1024) void thresh_k(const unsigned* __restrict__ hist,
                                                 float* __restrict__ T_lo) {
  __shared__ int suff[1024];
  int t = threadIdx.x;
  const int G = NBINS / 1024;
  int b0 = t * G;
  int s = 0;
  for (int j = 0; j < G; ++j) {
    unsigned tb = 0;
    for (int r = 0; r < NREP; ++r) tb += hist[(size_t)r * NBINS + b0 + j];
    s += (int)tb;
  }
  int v = s;
  suff[t] = v; __syncthreads();
  for (int o = 1; o < 1024; o <<= 1) {
    int add = (t + o < 1024) ? suff[t + o] : 0;
    __syncthreads();
    v += add; suff[t] = v;
    __syncthreads();
  }
  int above = (t < 1023) ? suff[t + 1] : 0;
  if (above < K_TOP && suff[t] >= K_TOP) {
    int running = above;
    int B = b0;
    for (int b = b0 + G - 1; b >= b0; --b) {
      unsigned tb = 0;
      for (int r = 0; r < NREP; ++r) tb += hist[(size_t)r * NBINS + b];
      running += (int)tb;
      if (running >= K_TOP) { B = b; break; }
    }
    B = max(B, SLACK_BINS);
    *T_lo = (float)(B - SLACK_BINS) * (1.0f / 4096.0f) - 1.0f;
  }
}

// ---------------- K10: compact candidates from S16, x4 MLP-unrolled ----------------
// Compares the SAME stored fp16 values hist binned — exactly consistent.
__global__ __launch_bounds__(256) void collect16_k(const f16x8* __restrict__ S8,
                                                   const float* __restrict__ T_lo_p,
                                                   unsigned* __restrict__ counter,
                                                   int* __restrict__ ci) {
  float T = *T_lo_p;
  const int stride = gridDim.x * blockDim.x;
  int i = blockIdx.x * blockDim.x + threadIdx.x;
#define SEL8(v, base)                                                        \
  _Pragma("unroll") for (int c = 0; c < 8; ++c) {                            \
    if ((float)(v)[c] >= T) {                                                \
      unsigned j = atomicAdd(counter, 1u);                                   \
      if (j < CAP2) ci[j] = (base) * 8 + c;                                  \
    }                                                                        \
  }
  for (; i + 3 * stride < S_TOTAL / 8; i += 4 * stride) {
    f16x8 v0 = S8[i];
    f16x8 v1 = S8[i + stride];
    f16x8 v2 = S8[i + 2 * stride];
    f16x8 v3 = S8[i + 3 * stride];
    SEL8(v0, i) SEL8(v1, i + stride) SEL8(v2, i + 2 * stride) SEL8(v3, i + 3 * stride)
  }
  for (; i < S_TOTAL / 8; i += stride) { f16x8 v = S8[i]; SEL8(v, i) }
#undef SEL8
}

// ---------------- K11: FULL f64 rescore -> monotone u64 key (1 wave / candidate) ----------------
__global__ __launch_bounds__(256) void rescore_k(const float* __restrict__ X,
                                                 const float* __restrict__ W,
                                                 const int* __restrict__ V,
                                                 const int* __restrict__ cnt,
                                                 const int* __restrict__ offs,
                                                 const int* __restrict__ bucket,
                                                 const int* __restrict__ ci,
                                                 const unsigned* __restrict__ counter,
                                                 unsigned long long* __restrict__ ckey) {
  int C = (int)min(*counter, (unsigned)CAP2);
  int wave = threadIdx.x >> 6, lane = threadIdx.x & 63;
  int j = blockIdx.x * 4 + wave;
  if (j >= C) return;
  int pos = ci[j];
  int n = pos >> 13;
  int m = pos & 8191;
  int deg = cnt[m], off = offs[m];
  int nmem = min(deg, 512);
  double e0 = 0.0, e1 = 0.0;
  for (int q = 0; q < nmem; ++q) {
    const float* xv = X + (size_t)V[bucket[off + q]] * EMB;
    e0 += (double)xv[lane];
    e1 += (double)xv[lane + 64];
  }
  double dd = fmax((double)deg, 1.0);
  e0 /= dd; e1 /= dd;
  const float* xr = X + (size_t)n * EMB;
  double x0 = (double)xr[lane], x1 = (double)xr[lane + 64];
  double s = 0.0;
  for (int h = 0; h < NHEAD; ++h) {
    const float* wr = W + h * EMB;
    double w0 = (double)wr[lane], w1 = (double)wr[lane + 64];
    double xw0 = x0 * w0, xw1 = x1 * w1;
    double ew0 = e0 * w0, ew1 = e1 * w1;
    double an = xw0 * xw0 + xw1 * xw1;
    double ae = ew0 * ew0 + ew1 * ew1;
    double dt = xw0 * ew0 + xw1 * ew1;
    for (int o = 32; o > 0; o >>= 1) {
      an += __shfl_down(an, o, 64);
      ae += __shfl_down(ae, o, 64);
      dt += __shfl_down(dt, o, 64);
    }
    if (lane == 0) {
      double Nn = fmax(sqrt(an), 1e-6);
      double Ne = fmax(sqrt(ae), 1e-6);
      s += dt / (Nn * Ne);
    }
  }
  if (lane == 0) ckey[j] = f64key(s * 0.25);
}

// ---------------- K12: exact k-th largest key via 8-level byte radix select ----------------
__global__ __launch_bounds__(1024) void kth_k(const unsigned long long* __restrict__ keys,
                                              const unsigned* __restrict__ counter,
                                              unsigned long long* __restrict__ thr) {
  __shared__ unsigned hist[256];
  __shared__ unsigned long long s_prefix;
  __shared__ unsigned s_kleft, s_cgreat;
  int C = (int)min(*counter, (unsigned)CAP2);
  if (threadIdx.x == 0) { s_prefix = 0ULL; s_kleft = K_TOP; s_cgreat = 0u; }
  __syncthreads();
  for (int level = 7; level >= 0; --level) {
    for (int i = threadIdx.x; i < 256; i += 1024) hist[i] = 0;
    __syncthreads();
    unsigned long long prefix = s_prefix;
    unsigned long long pmask = (level == 7) ? 0ULL : (~0ULL << ((level + 1) * 8));
    for (int i = threadIdx.x; i < C; i += 1024) {
      unsigned long long k = keys[i];
      if ((k & pmask) == prefix)
        atomicAdd(&hist[(unsigned)((k >> (level * 8)) & 0xFF)], 1u);
    }
    __syncthreads();
    if (threadIdx.x == 0) {
      unsigned cum = 0; int b = 0;
      for (int i = 255; i >= 0; --i) {
        if (cum + hist[i] >= s_kleft) { b = i; break; }
        cum += hist[i];
      }
      s_prefix |= ((unsigned long long)b << (level * 8));
      s_kleft  -= cum;
      s_cgreat += cum;
    }
    __syncthreads();
  }
  if (threadIdx.x == 0) { thr[0] = s_prefix; thr[1] = (unsigned long long)s_cgreat; }
}

// ---------------- K13: write masks for key > thr; gather ties at key == thr ----------------
__global__ void write_k(const unsigned long long* __restrict__ keys,
                        const int* __restrict__ ci,
                        const unsigned* __restrict__ counter,
                        const unsigned long long* __restrict__ thr,
                        const float* __restrict__ P, float* __restrict__ out,
                        int* __restrict__ tiebuf, unsigned* __restrict__ tiecnt) {
  int C = (int)min(*counter, (unsigned)CAP2);
  int j = blockIdx.x * blockDim.x + threadIdx.x;
  if (j >= C) return;
  unsigned long long k = keys[j];
  unsigned long long t = thr[0];
  if (k > t) {
    unsigned pos = (unsigned)ci[j];
    out[pos] = mask_val(P[pos], pos);
  } else if (k == t) {
    unsigned q = atomicAdd(tiecnt, 1u);
    if (q < TIE_CAP) tiebuf[q] = ci[j];
  }
}

// ---------------- K14: fill remaining slots from ties, ascending index ----------------
__global__ __launch_bounds__(256) void tiefin_k(const int* __restrict__ tiebuf,
                                                const unsigned* __restrict__ tiecnt,
                                                const unsigned long long* __restrict__ thr,
                                                const float* __restrict__ P,
                                                float* __restrict__ out) {
  __shared__ int idx[TIE_CAP];
  int T = (int)min(*tiecnt, (unsigned)TIE_CAP);
  int need = K_TOP - (int)thr[1];
  if (need <= 0 || T == 0) return;       // uniform exit
  for (int i = threadIdx.x; i < T; i += 256) idx[i] = tiebuf[i];
  __syncthreads();
  if (threadIdx.x == 0 && T > 1) {       // ascending flat index (top_k stable order)
    for (int a = 1; a < T; ++a) {
      int key = idx[a]; int b = a - 1;
      while (b >= 0 && idx[b] > key) { idx[b + 1] = idx[b]; --b; }
      idx[b + 1] = key;
    }
  }
  __syncthreads();
  int m = min(need, T);
  for (int i = threadIdx.x; i < m; i += 256) {
    unsigned pos = (unsigned)idx[i];
    out[pos] = mask_val(P[pos], pos);
  }
}

// ---------------- K15: H positions (the (V,E) pairs) ----------------
__global__ void scatterH_k(const int* __restrict__ V, const int* __restrict__ E,
                           const float* __restrict__ P, float* __restrict__ out) {
  int i = blockIdx.x * blockDim.x + threadIdx.x;
  if (i >= NNZ) return;
  unsigned pos = (unsigned)V[i] * (unsigned)N_EDGES + (unsigned)E[i];
  out[pos] = mask_val(P[pos], pos);
}

extern "C" void kernel_launch(void* const* d_in, const int* in_sizes, int n_in,
                              void* d_out, int out_size, void* d_ws, size_t ws_size,
                              hipStream_t stream) {
  const float* X = (const float*)d_in[0];
  // d_in[1] = H (unused: nonzeros are exactly the (V,E) pairs)
  const int*   V = (const int*)d_in[2];
  const int*   E = (const int*)d_in[3];
  const float* P = (const float*)d_in[4];
  const float* W = (const float*)d_in[5];
  float* OUT = (float*)d_out;

  // S16 (fp16 scores, 64 MB) lives in the UPPER HALF of d_out; consumed by
  // maskset16/hist16/collect16, then the full d_out is memset before final writes.
  unsigned short* S16 = (unsigned short*)((char*)d_out + (size_t)S_TOTAL * 2);

  // ws layout — ~14.5 MB. ghist ALIASES cand_idx (lifetimes disjoint:
  // ghist dies at thresh_k; cand_idx born at collect16_k).
  char* w = (char*)d_ws;
  int*      cnt      = (int*)(w + 0);            // 32 KB
  int*      offs     = (int*)(w + 32768);        // 32 KB
  int*      cursor   = (int*)(w + 65536);        // 32 KB
  int*      bucket   = (int*)(w + 98304);        // 256 KB -> 360448
  unsigned* counter  = (unsigned*)(w + 360448);  // 4 B
  float*    T_lo     = (float*)(w + 360452);     // 4 B
  unsigned* tiecnt   = (unsigned*)(w + 360456);  // 4 B
  unsigned long long* thr = (unsigned long long*)(w + 360464); // 16 B
  int*      cand_idx = (int*)(w + 360704);       // 512 KB -> 884992
  unsigned* ghist    = (unsigned*)(w + 360704);  // 512 KB alias (16 x 8192 x 4 B)
  unsigned long long* cand_key = (unsigned long long*)(w + 884992); // 1 MB -> 1933568
  int*      tiebuf   = (int*)(w + 1933568);      // 4 KB   -> 1937664
  f16_t*    A16      = (f16_t*)(w + 1937664);    // 4 MB   -> 6131968 (16B aligned)
  f16_t*    B16      = (f16_t*)(w + 6131968);    // 8 MB   -> 14520576 (16B aligned)

  hipMemsetAsync(cnt,     0, 32768, stream);
  hipMemsetAsync(cursor,  0, 32768, stream);
  hipMemsetAsync((void*)(w + 360448), 0, 64, stream);   // counter, T_lo, tiecnt, thr
  hipMemsetAsync(ghist,   0, (size_t)NREP * NBINS * 4, stream);

  count_k     <<<NNZ / 256, 256, 0, stream>>>(E, cnt);
  scan_k      <<<1, 1024, 0, stream>>>(cnt, offs);
  scatter_k   <<<NNZ / 256, 256, 0, stream>>>(E, offs, cursor, bucket);
  edge_k      <<<N_EDGES, 128, 0, stream>>>(X, V, cnt, offs, bucket, W, B16);
  node_k      <<<N_CODES, 128, 0, stream>>>(X, W, A16);
  gemm_k      <<<dim3(N_EDGES / 128, N_CODES / 128), 256, 0, stream>>>(A16, B16, S16);
  maskset16_k <<<NNZ / 256, 256, 0, stream>>>(V, E, S16);
  hist16_k    <<<1024, 256, 0, stream>>>((const f16x8*)S16, ghist);
  thresh_k    <<<1, 1024, 0, stream>>>(ghist, T_lo);
  collect16_k <<<1024, 256, 0, stream>>>((const f16x8*)S16, T_lo, counter, cand_idx);
  rescore_k   <<<CAP2 / 4, 256, 0, stream>>>(X, W, V, cnt, offs, bucket,
                                             cand_idx, counter, cand_key);
  kth_k       <<<1, 1024, 0, stream>>>(cand_key, counter, thr);
  hipMemsetAsync(d_out, 0, (size_t)S_TOTAL * 4, stream);  // after S16 consumed
  write_k     <<<CAP2 / 256, 256, 0, stream>>>(cand_key, cand_idx, counter, thr,
                                               P, OUT, tiebuf, tiecnt);
  tiefin_k    <<<1, 256, 0, stream>>>(tiebuf, tiecnt, thr, P, OUT);
  scatterH_k  <<<NNZ / 256, 256, 0, stream>>>(V, E, P, OUT);
}

// Round 5
// 501.051 us; speedup vs baseline: 1.3109x; 1.1666x over previous
//
#include <hip/hip_runtime.h>
#include <math.h>

#define N_CODES 4096
#define N_EDGES 8192
#define EMB     128
#define NHEAD   4
#define NNZ     65536
#define K_TOP   6553            // int(0.1 * 65536)
#define K_SAMP  820             // ceil(K_TOP / 8) for the 1/8-sampled histogram
#define S_TOTAL 33554432        // 4096 * 8192
#define NBINS   8192            // 32 KB LDS histogram
#define NREP    16              // global hist replicas (atomic contention /16)
#define CAP2    131072          // candidate cap (pool ~50k at 14-bin slack)
#define SLACK_BINS 14           // 12 (fp16 + GEMM noise) + 2 (1/8-sampling margin)
#define TIE_CAP 1024
#define LBUF    4096            // per-block candidate buffer (16 KB LDS)
#define SAMP_ITEMS (S_TOTAL / 8 / 8)   // 524288 sampled f16x8 items

typedef _Float16 f16_t;
typedef __attribute__((ext_vector_type(8))) _Float16 f16x8;
typedef __attribute__((ext_vector_type(4))) float f32x4;

// ---------------- threefry2x32, JAX partitionable scheme, 32-bit path ----------------
__device__ __forceinline__ unsigned rotl32(unsigned v, int r) {
  return (v << r) | (v >> (32 - r));
}

__device__ float jax_u42(unsigned pos) {
  const unsigned ks0 = 0u, ks1 = 42u, ks2 = 0x1BD11BDAu ^ 0u ^ 42u;
  unsigned x0 = 0u  + ks0;
  unsigned x1 = pos + ks1;
#define TFR(r) { x0 += x1; x1 = rotl32(x1, (r)); x1 ^= x0; }
  TFR(13) TFR(15) TFR(26) TFR(6)   x0 += ks1; x1 += ks2 + 1u;
  TFR(17) TFR(29) TFR(16) TFR(24)  x0 += ks2; x1 += ks0 + 2u;
  TFR(13) TFR(15) TFR(26) TFR(6)   x0 += ks0; x1 += ks1 + 3u;
  TFR(17) TFR(29) TFR(16) TFR(24)  x0 += ks1; x1 += ks2 + 4u;
  TFR(13) TFR(15) TFR(26) TFR(6)   x0 += ks2; x1 += ks0 + 5u;
#undef TFR
  unsigned bits = x0 ^ x1;
  unsigned fb = (bits >> 9) | 0x3f800000u;
  float f = __uint_as_float(fb) - 1.0f;
  const float minv = 1e-6f;
  const float maxv = (float)(1.0 - 1e-6);
  float u = f * (maxv - minv) + minv;
  return fmaxf(minv, u);
}

__device__ float mask_val(float p, unsigned pos) {
  float u = jax_u42(pos);
  float l = (logf(p) - log1pf(-p) + logf(u) - log1pf(-u)) * 2.0f; // /TEMP, TEMP=0.5
  return 1.0f / (1.0f + expf(-l));
}

// f64 -> u64 monotone key (larger double <=> larger key)
__device__ __forceinline__ unsigned long long f64key(double v) {
  long long b = __double_as_longlong(v);
  return (b < 0) ? ~(unsigned long long)b
                 : ((unsigned long long)b | 0x8000000000000000ULL);
}

// ---------------- K1: per-edge counts ----------------
__global__ void count_k(const int* __restrict__ E, int* __restrict__ cnt) {
  int i = blockIdx.x * blockDim.x + threadIdx.x;
  if (i < NNZ) atomicAdd(&cnt[E[i]], 1);
}

// ---------------- K2: exclusive scan of 8192 counts ----------------
__global__ __launch_bounds__(1024) void scan_k(const int* __restrict__ cnt,
                                               int* __restrict__ offs) {
  __shared__ int part[1024];
  int t = threadIdx.x;
  int local[8]; int s = 0;
  for (int j = 0; j < 8; ++j) { local[j] = cnt[t * 8 + j]; s += local[j]; }
  part[t] = s; __syncthreads();
  int v = s;
  for (int o = 1; o < 1024; o <<= 1) {
    int add = (t >= o) ? part[t - o] : 0;
    __syncthreads();
    v += add; part[t] = v;
    __syncthreads();
  }
  int base = v - s;
  for (int j = 0; j < 8; ++j) { offs[t * 8 + j] = base; base += local[j]; }
}

// ---------------- K3: bucket scatter (CSR) ----------------
__global__ void scatter_k(const int* __restrict__ E, const int* __restrict__ offs,
                          int* __restrict__ cursor, int* __restrict__ bucket) {
  int i = blockIdx.x * blockDim.x + threadIdx.x;
  if (i < NNZ) {
    int e = E[i];
    int p = atomicAdd(&cursor[e], 1);
    bucket[offs[e] + p] = i;
  }
}

// ---------------- K4: sort CSR lists, fused-normalized fp16 B operand ----------------
// B16[m][h*128+d] = eX[m][d] * W[h][d]^2 * (1/max(||eX_m o W_h||,1e-6))
__global__ __launch_bounds__(128) void edge_k(const float* __restrict__ X,
                                              const int* __restrict__ V,
                                              const int* __restrict__ cnt,
                                              const int* __restrict__ offs,
                                              int* __restrict__ bucket,
                                              const float* __restrict__ W,
                                              f16_t* __restrict__ B16) {
  __shared__ int lst[512];
  __shared__ float red[2];
  int m = blockIdx.x, t = threadIdx.x;
  int deg = cnt[m], off = offs[m];
  int n = min(deg, 512);
  for (int j = t; j < n; j += 128) lst[j] = bucket[off + j];
  __syncthreads();
  if (t == 0 && n > 1) {             // ascending-index order == np.add.at order
    for (int a = 1; a < n; ++a) {
      int key = lst[a]; int b = a - 1;
      while (b >= 0 && lst[b] > key) { lst[b + 1] = lst[b]; --b; }
      lst[b + 1] = key;
    }
  }
  __syncthreads();
  for (int j = t; j < n; j += 128) bucket[off + j] = lst[j];  // sorted CSR for rescore
  float s = 0.f;
  for (int j = 0; j < n; ++j) s += X[(size_t)V[lst[j]] * EMB + t];
  float eXd = s / fmaxf((float)deg, 1.0f);
  int lane = t & 63, wv = t >> 6;
  for (int h = 0; h < NHEAD; ++h) {
    float wd = W[h * EMB + t];
    float val = eXd * wd;
    float ss = val * val;
    for (int o = 32; o > 0; o >>= 1) ss += __shfl_down(ss, o, 64);
    if (lane == 0) red[wv] = ss;
    __syncthreads();
    float nh = 1.0f / fmaxf(sqrtf(red[0] + red[1]), 1e-6f);
    B16[(size_t)m * (NHEAD * EMB) + h * EMB + t] = (f16_t)(eXd * wd * wd * nh);
    __syncthreads();
  }
}

// ---------------- K5: fused-normalized fp16 A operand ----------------
// A16[n][h*128+d] = X[n][d] * (1/max(||X_n o W_h||,1e-6))   (W^2 folded into B side)
__global__ __launch_bounds__(128) void node_k(const float* __restrict__ X,
                                              const float* __restrict__ W,
                                              f16_t* __restrict__ A16) {
  __shared__ float red[2];
  int nid = blockIdx.x, t = threadIdx.x;
  float xd = X[(size_t)nid * EMB + t];
  int lane = t & 63, wv = t >> 6;
  for (int h = 0; h < NHEAD; ++h) {
    float val = xd * W[h * EMB + t];
    float ss = val * val;
    for (int o = 32; o > 0; o >>= 1) ss += __shfl_down(ss, o, 64);
    if (lane == 0) red[wv] = ss;
    __syncthreads();
    float nh = 1.0f / fmaxf(sqrtf(red[0] + red[1]), 1e-6f);
    A16[(size_t)nid * (NHEAD * EMB) + h * EMB + t] = (f16_t)(xd * nh);
    __syncthreads();
  }
}

// ---------------- K6: fp16 MFMA GEMM (R1-proven structure) -> S16 ----------------
// m97 structure: 128x128 tile, 4 waves (2x2 of 64x64), BK=32, 16x16x32 MFMA,
// global_load_lds width=16 staging, source-side XOR swizzle (rule #21).
__global__ __launch_bounds__(256) void gemm_k(const f16_t* __restrict__ A16,
                                              const f16_t* __restrict__ B16,
                                              unsigned short* __restrict__ S16) {
  __shared__ __align__(16) f16_t As[128 * 32];
  __shared__ __align__(16) f16_t Bs[128 * 32];
  const int tid  = threadIdx.x;
  const int lane = tid & 63;
  const int wv   = tid >> 6;
  const int m0   = blockIdx.x * 128;       // edge cols
  const int n0   = blockIdx.y * 128;       // node rows
  const int wr   = (wv >> 1) * 64;
  const int wc   = (wv & 1) * 64;
  const int frow = lane & 15;
  const int fg   = lane >> 4;
  const int sw   = (frow >> 1) & 3;
  const int fo   = ((fg ^ sw) << 3);

  f32x4 acc[4][4];
#pragma unroll
  for (int i = 0; i < 4; ++i)
#pragma unroll
    for (int j = 0; j < 4; ++j) acc[i][j] = (f32x4){0.f, 0.f, 0.f, 0.f};

  for (int k0 = 0; k0 < 512; k0 += 32) {
    __syncthreads();
#pragma unroll
    for (int r = 0; r < 2; ++r) {
      int chunk = r * 256 + wv * 64 + lane;
      int row   = chunk >> 2;
      int cb    = ((chunk & 3) ^ ((chunk >> 3) & 3)) << 3;
      __builtin_amdgcn_global_load_lds(
          (const __attribute__((address_space(1))) void*)
              (A16 + ((size_t)(n0 + row) << 9) + k0 + cb),
          (__attribute__((address_space(3))) void*)
              (As + (size_t)(r * 256 + wv * 64) * 8),
          16, 0, 0);
      __builtin_amdgcn_global_load_lds(
          (const __attribute__((address_space(1))) void*)
              (B16 + ((size_t)(m0 + row) << 9) + k0 + cb),
          (__attribute__((address_space(3))) void*)
              (Bs + (size_t)(r * 256 + wv * 64) * 8),
          16, 0, 0);
    }
    __syncthreads();
    f16x8 a[4], b[4];
#pragma unroll
    for (int i = 0; i < 4; ++i)
      a[i] = *(const f16x8*)(As + (wr + i * 16 + frow) * 32 + fo);
#pragma unroll
    for (int j = 0; j < 4; ++j)
      b[j] = *(const f16x8*)(Bs + (wc + j * 16 + frow) * 32 + fo);
#pragma unroll
    for (int i = 0; i < 4; ++i)
#pragma unroll
      for (int j = 0; j < 4; ++j)
        acc[i][j] = __builtin_amdgcn_mfma_f32_16x16x32_f16(a[i], b[j], acc[i][j], 0, 0, 0);
  }
  // C/D layout (m89-verified): col = lane&15, row = (lane>>4)*4 + q
#pragma unroll
  for (int i = 0; i < 4; ++i)
#pragma unroll
    for (int q = 0; q < 4; ++q) {
      int row = n0 + wr + i * 16 + fg * 4 + q;
      unsigned short* Sr = S16 + (size_t)row * N_EDGES + m0 + wc;
#pragma unroll
      for (int j = 0; j < 4; ++j) {
        f16_t h = (f16_t)(acc[i][j][q] * 0.25f);
        Sr[j * 16 + frow] = __builtin_bit_cast(unsigned short, h);
      }
    }
}

// ---------------- K7: mask existing incidences in S16 (fp16 -inf) ----------------
__global__ void maskset16_k(const int* __restrict__ V, const int* __restrict__ E,
                            unsigned short* __restrict__ S16) {
  int i = blockIdx.x * blockDim.x + threadIdx.x;
  if (i < NNZ) S16[(size_t)V[i] * N_EDGES + E[i]] = 0xFC00u;  // -inf
}

// ---------------- K8: 1/8-SAMPLED 8192-bin histogram over S16 ----------------
// Threshold selection needs the k-th QUANTILE, not exact counts. Sample pattern:
// 64 consecutive f16x8 items every 512 (wave reads stay 1 KB coalesced; rows are
// 1024 items, a multiple of 512, so EVERY row is sampled exactly 128 items —
// per-row uniform). thresh_k compares the sampled suffix to K_SAMP=ceil(K_TOP/8);
// sampling shifts the picked bin by <=2 bins at 6 sigma — covered by SLACK_BINS.
__global__ __launch_bounds__(256) void hist16_k(const f16x8* __restrict__ S8,
                                                unsigned* __restrict__ ghist) {
  __shared__ unsigned hh[NBINS];
  for (int i = threadIdx.x; i < NBINS; i += 256) hh[i] = 0;
  __syncthreads();
  const int stride = gridDim.x * blockDim.x;     // multiple of 64
  int j = blockIdx.x * blockDim.x + threadIdx.x;
#define BIN8(v)                                                              \
  _Pragma("unroll") for (int c = 0; c < 8; ++c) {                            \
    float bf = fminf(fmaxf(((float)(v)[c] + 1.0f) * 4096.0f, 0.0f),          \
                     (float)(NBINS - 1));                                    \
    atomicAdd(&hh[(int)bf], 1u);                                             \
  }
#define SIDX(jj) (((jj) >> 6) * 512 + ((jj) & 63))
  for (; j + 3 * stride < SAMP_ITEMS; j += 4 * stride) {
    f16x8 v0 = S8[SIDX(j)];
    f16x8 v1 = S8[SIDX(j + stride)];
    f16x8 v2 = S8[SIDX(j + 2 * stride)];
    f16x8 v3 = S8[SIDX(j + 3 * stride)];
    BIN8(v0) BIN8(v1) BIN8(v2) BIN8(v3)
  }
  for (; j < SAMP_ITEMS; j += stride) { f16x8 v = S8[SIDX(j)]; BIN8(v) }
#undef SIDX
#undef BIN8
  __syncthreads();
  unsigned* gh = ghist + (size_t)(blockIdx.x & (NREP - 1)) * NBINS;
  for (int i2 = threadIdx.x; i2 < NBINS; i2 += 256) {
    unsigned c = hh[i2];
    if (c) atomicAdd(&gh[i2], c);
  }
}

// ---------------- K9: screening threshold from the SAMPLED hist ----------------
__global__ __launch_bounds__(1024) void thresh_k(const unsigned* __restrict__ hist,
                                                 float* __restrict__ T_lo) {
  __shared__ int suff[1024];
  int t = threadIdx.x;
  const int G = NBINS / 1024;
  int b0 = t * G;
  int s = 0;
  for (int j = 0; j < G; ++j) {
    unsigned tb = 0;
    for (int r = 0; r < NREP; ++r) tb += hist[(size_t)r * NBINS + b0 + j];
    s += (int)tb;
  }
  int v = s;
  suff[t] = v; __syncthreads();
  for (int o = 1; o < 1024; o <<= 1) {
    int add = (t + o < 1024) ? suff[t + o] : 0;
    __syncthreads();
    v += add; suff[t] = v;
    __syncthreads();
  }
  int above = (t < 1023) ? suff[t + 1] : 0;
  if (above < K_SAMP && suff[t] >= K_SAMP) {
    int running = above;
    int B = b0;
    for (int b = b0 + G - 1; b >= b0; --b) {
      unsigned tb = 0;
      for (int r = 0; r < NREP; ++r) tb += hist[(size_t)r * NBINS + b];
      running += (int)tb;
      if (running >= K_SAMP) { B = b; break; }
    }
    B = max(B, SLACK_BINS);
    *T_lo = (float)(B - SLACK_BINS) * (1.0f / 4096.0f) - 1.0f;
  }
}

// ---------------- K10: compact candidates, two-level counter ----------------
// R1/R4 PMC: dur invariant at ~89us under 2x traffic change, VALUBusy 2.4%,
// VGPR=12 — the ~45k SAME-ADDRESS global atomics serialized at one L2 slice AND
// blocked load pipelining. Fix: hits -> per-block LDS buffer (LDS atomics are
// addrspace(3): provably no-alias with the S16 loads, so loads pipeline; LDS RMW
// is distributed over 1024 blocks). ONE global atomic per block reserves a range.
__global__ __launch_bounds__(256) void collect16_k(const f16x8* __restrict__ S8,
                                                   const float* __restrict__ T_lo_p,
                                                   unsigned* __restrict__ counter,
                                                   int* __restrict__ ci) {
  __shared__ int lbuf[LBUF];
  __shared__ unsigned lcnt, gbase;
  if (threadIdx.x == 0) lcnt = 0;
  __syncthreads();
  float T = *T_lo_p;
  const int stride = gridDim.x * blockDim.x;
  int i = blockIdx.x * blockDim.x + threadIdx.x;
#define SEL8(v, base)                                                        \
  _Pragma("unroll") for (int c = 0; c < 8; ++c) {                            \
    if ((float)(v)[c] >= T) {                                                \
      unsigned j = atomicAdd(&lcnt, 1u);                                     \
      if (j < LBUF) lbuf[j] = (base) * 8 + c;                                \
      else { unsigned g = atomicAdd(counter, 1u);                            \
             if (g < CAP2) ci[g] = (base) * 8 + c; }                         \
    }                                                                        \
  }
  for (; i + 3 * stride < S_TOTAL / 8; i += 4 * stride) {
    f16x8 v0 = S8[i];
    f16x8 v1 = S8[i + stride];
    f16x8 v2 = S8[i + 2 * stride];
    f16x8 v3 = S8[i + 3 * stride];
    SEL8(v0, i) SEL8(v1, i + stride) SEL8(v2, i + 2 * stride) SEL8(v3, i + 3 * stride)
  }
  for (; i < S_TOTAL / 8; i += stride) { f16x8 v = S8[i]; SEL8(v, i) }
#undef SEL8
  __syncthreads();
  unsigned n = min(lcnt, (unsigned)LBUF);
  if (threadIdx.x == 0) gbase = atomicAdd(counter, n);
  __syncthreads();
  unsigned gb = gbase;
  for (unsigned t = threadIdx.x; t < n; t += 256) {
    unsigned p = gb + t;
    if (p < CAP2) ci[p] = lbuf[t];
  }
}

// ---------------- K11: FULL f64 rescore -> monotone u64 key (1 wave / candidate) ----------------
__global__ __launch_bounds__(256) void rescore_k(const float* __restrict__ X,
                                                 const float* __restrict__ W,
                                                 const int* __restrict__ V,
                                                 const int* __restrict__ cnt,
                                                 const int* __restrict__ offs,
                                                 const int* __restrict__ bucket,
                                                 const int* __restrict__ ci,
                                                 const unsigned* __restrict__ counter,
                                                 unsigned long long* __restrict__ ckey) {
  int C = (int)min(*counter, (unsigned)CAP2);
  int wave = threadIdx.x >> 6, lane = threadIdx.x & 63;
  int j = blockIdx.x * 4 + wave;
  if (j >= C) return;
  int pos = ci[j];
  int n = pos >> 13;
  int m = pos & 8191;
  int deg = cnt[m], off = offs[m];
  int nmem = min(deg, 512);
  double e0 = 0.0, e1 = 0.0;
  for (int q = 0; q < nmem; ++q) {
    const float* xv = X + (size_t)V[bucket[off + q]] * EMB;
    e0 += (double)xv[lane];
    e1 += (double)xv[lane + 64];
  }
  double dd = fmax((double)deg, 1.0);
  e0 /= dd; e1 /= dd;
  const float* xr = X + (size_t)n * EMB;
  double x0 = (double)xr[lane], x1 = (double)xr[lane + 64];
  double s = 0.0;
  for (int h = 0; h < NHEAD; ++h) {
    const float* wr = W + h * EMB;
    double w0 = (double)wr[lane], w1 = (double)wr[lane + 64];
    double xw0 = x0 * w0, xw1 = x1 * w1;
    double ew0 = e0 * w0, ew1 = e1 * w1;
    double an = xw0 * xw0 + xw1 * xw1;
    double ae = ew0 * ew0 + ew1 * ew1;
    double dt = xw0 * ew0 + xw1 * ew1;
    for (int o = 32; o > 0; o >>= 1) {
      an += __shfl_down(an, o, 64);
      ae += __shfl_down(ae, o, 64);
      dt += __shfl_down(dt, o, 64);
    }
    if (lane == 0) {
      double Nn = fmax(sqrt(an), 1e-6);
      double Ne = fmax(sqrt(ae), 1e-6);
      s += dt / (Nn * Ne);
    }
  }
  if (lane == 0) ckey[j] = f64key(s * 0.25);
}

// ---------------- K12: exact k-th largest key via 8-level byte radix select ----------------
__global__ __launch_bounds__(1024) void kth_k(const unsigned long long* __restrict__ keys,
                                              const unsigned* __restrict__ counter,
                                              unsigned long long* __restrict__ thr) {
  __shared__ unsigned hist[256];
  __shared__ unsigned long long s_prefix;
  __shared__ unsigned s_kleft, s_cgreat;
  int C = (int)min(*counter, (unsigned)CAP2);
  if (threadIdx.x == 0) { s_prefix = 0ULL; s_kleft = K_TOP; s_cgreat = 0u; }
  __syncthreads();
  for (int level = 7; level >= 0; --level) {
    for (int i = threadIdx.x; i < 256; i += 1024) hist[i] = 0;
    __syncthreads();
    unsigned long long prefix = s_prefix;
    unsigned long long pmask = (level == 7) ? 0ULL : (~0ULL << ((level + 1) * 8));
    for (int i = threadIdx.x; i < C; i += 1024) {
      unsigned long long k = keys[i];
      if ((k & pmask) == prefix)
        atomicAdd(&hist[(unsigned)((k >> (level * 8)) & 0xFF)], 1u);
    }
    __syncthreads();
    if (threadIdx.x == 0) {
      unsigned cum = 0; int b = 0;
      for (int i = 255; i >= 0; --i) {
        if (cum + hist[i] >= s_kleft) { b = i; break; }
        cum += hist[i];
      }
      s_prefix |= ((unsigned long long)b << (level * 8));
      s_kleft  -= cum;
      s_cgreat += cum;
    }
    __syncthreads();
  }
  if (threadIdx.x == 0) { thr[0] = s_prefix; thr[1] = (unsigned long long)s_cgreat; }
}

// ---------------- K13: write masks for key > thr; gather ties at key == thr ----------------
__global__ void write_k(const unsigned long long* __restrict__ keys,
                        const int* __restrict__ ci,
                        const unsigned* __restrict__ counter,
                        const unsigned long long* __restrict__ thr,
                        const float* __restrict__ P, float* __restrict__ out,
                        int* __restrict__ tiebuf, unsigned* __restrict__ tiecnt) {
  int C = (int)min(*counter, (unsigned)CAP2);
  int j = blockIdx.x * blockDim.x + threadIdx.x;
  if (j >= C) return;
  unsigned long long k = keys[j];
  unsigned long long t = thr[0];
  if (k > t) {
    unsigned pos = (unsigned)ci[j];
    out[pos] = mask_val(P[pos], pos);
  } else if (k == t) {
    unsigned q = atomicAdd(tiecnt, 1u);
    if (q < TIE_CAP) tiebuf[q] = ci[j];
  }
}

// ---------------- K14: fill remaining slots from ties, ascending index ----------------
__global__ __launch_bounds__(256) void tiefin_k(const int* __restrict__ tiebuf,
                                                const unsigned* __restrict__ tiecnt,
                                                const unsigned long long* __restrict__ thr,
                                                const float* __restrict__ P,
                                                float* __restrict__ out) {
  __shared__ int idx[TIE_CAP];
  int T = (int)min(*tiecnt, (unsigned)TIE_CAP);
  int need = K_TOP - (int)thr[1];
  if (need <= 0 || T == 0) return;       // uniform exit
  for (int i = threadIdx.x; i < T; i += 256) idx[i] = tiebuf[i];
  __syncthreads();
  if (threadIdx.x == 0 && T > 1) {       // ascending flat index (top_k stable order)
    for (int a = 1; a < T; ++a) {
      int key = idx[a]; int b = a - 1;
      while (b >= 0 && idx[b] > key) { idx[b + 1] = idx[b]; --b; }
      idx[b + 1] = key;
    }
  }
  __syncthreads();
  int m = min(need, T);
  for (int i = threadIdx.x; i < m; i += 256) {
    unsigned pos = (unsigned)idx[i];
    out[pos] = mask_val(P[pos], pos);
  }
}

// ---------------- K15: H positions (the (V,E) pairs) ----------------
__global__ void scatterH_k(const int* __restrict__ V, const int* __restrict__ E,
                           const float* __restrict__ P, float* __restrict__ out) {
  int i = blockIdx.x * blockDim.x + threadIdx.x;
  if (i >= NNZ) return;
  unsigned pos = (unsigned)V[i] * (unsigned)N_EDGES + (unsigned)E[i];
  out[pos] = mask_val(P[pos], pos);
}

extern "C" void kernel_launch(void* const* d_in, const int* in_sizes, int n_in,
                              void* d_out, int out_size, void* d_ws, size_t ws_size,
                              hipStream_t stream) {
  const float* X = (const float*)d_in[0];
  // d_in[1] = H (unused: nonzeros are exactly the (V,E) pairs)
  const int*   V = (const int*)d_in[2];
  const int*   E = (const int*)d_in[3];
  const float* P = (const float*)d_in[4];
  const float* W = (const float*)d_in[5];
  float* OUT = (float*)d_out;

  // S16 (fp16 scores, 64 MB) lives in the UPPER HALF of d_out; consumed by
  // maskset16/hist16/collect16, then the full d_out is memset before final writes.
  unsigned short* S16 = (unsigned short*)((char*)d_out + (size_t)S_TOTAL * 2);

  // ws layout — ~14.5 MB. ghist ALIASES cand_idx (lifetimes disjoint:
  // ghist dies at thresh_k; cand_idx born at collect16_k).
  char* w = (char*)d_ws;
  int*      cnt      = (int*)(w + 0);            // 32 KB
  int*      offs     = (int*)(w + 32768);        // 32 KB
  int*      cursor   = (int*)(w + 65536);        // 32 KB
  int*      bucket   = (int*)(w + 98304);        // 256 KB -> 360448
  unsigned* counter  = (unsigned*)(w + 360448);  // 4 B
  float*    T_lo     = (float*)(w + 360452);     // 4 B
  unsigned* tiecnt   = (unsigned*)(w + 360456);  // 4 B
  unsigned long long* thr = (unsigned long long*)(w + 360464); // 16 B
  int*      cand_idx = (int*)(w + 360704);       // 512 KB -> 884992
  unsigned* ghist    = (unsigned*)(w + 360704);  // 512 KB alias (16 x 8192 x 4 B)
  unsigned long long* cand_key = (unsigned long long*)(w + 884992); // 1 MB -> 1933568
  int*      tiebuf   = (int*)(w + 1933568);      // 4 KB   -> 1937664
  f16_t*    A16      = (f16_t*)(w + 1937664);    // 4 MB   -> 6131968 (16B aligned)
  f16_t*    B16      = (f16_t*)(w + 6131968);    // 8 MB   -> 14520576 (16B aligned)

  hipMemsetAsync(cnt,     0, 32768, stream);
  hipMemsetAsync(cursor,  0, 32768, stream);
  hipMemsetAsync((void*)(w + 360448), 0, 64, stream);   // counter, T_lo, tiecnt, thr
  hipMemsetAsync(ghist,   0, (size_t)NREP * NBINS * 4, stream);

  count_k     <<<NNZ / 256, 256, 0, stream>>>(E, cnt);
  scan_k      <<<1, 1024, 0, stream>>>(cnt, offs);
  scatter_k   <<<NNZ / 256, 256, 0, stream>>>(E, offs, cursor, bucket);
  edge_k      <<<N_EDGES, 128, 0, stream>>>(X, V, cnt, offs, bucket, W, B16);
  node_k      <<<N_CODES, 128, 0, stream>>>(X, W, A16);
  gemm_k      <<<dim3(N_EDGES / 128, N_CODES / 128), 256, 0, stream>>>(A16, B16, S16);
  maskset16_k <<<NNZ / 256, 256, 0, stream>>>(V, E, S16);
  hist16_k    <<<256, 256, 0, stream>>>((const f16x8*)S16, ghist);
  thresh_k    <<<1, 1024, 0, stream>>>(ghist, T_lo);
  collect16_k <<<1024, 256, 0, stream>>>((const f16x8*)S16, T_lo, counter, cand_idx);
  rescore_k   <<<CAP2 / 4, 256, 0, stream>>>(X, W, V, cnt, offs, bucket,
                                             cand_idx, counter, cand_key);
  kth_k       <<<1, 1024, 0, stream>>>(cand_key, counter, thr);
  hipMemsetAsync(d_out, 0, (size_t)S_TOTAL * 4, stream);  // after S16 consumed
  write_k     <<<CAP2 / 256, 256, 0, stream>>>(cand_key, cand_idx, counter, thr,
                                               P, OUT, tiebuf, tiecnt);
  tiefin_k    <<<1, 256, 0, stream>>>(tiebuf, tiecnt, thr, P, OUT);
  scatterH_k  <<<NNZ / 256, 256, 0, stream>>>(V, E, P, OUT);
}

// Round 6
// 498.619 us; speedup vs baseline: 1.3173x; 1.0049x over previous
//
#include <hip/hip_runtime.h>
#include <math.h>

#define N_CODES 4096
#define N_EDGES 8192
#define EMB     128
#define NHEAD   4
#define NNZ     65536
#define K_TOP   6553            // int(0.1 * 65536)
#define K_SAMP  820             // ceil(K_TOP / 8) for the 1/8-sampled histogram
#define S_TOTAL 33554432        // 4096 * 8192
#define NBINS   8192            // 32 KB LDS histogram
#define NREP    16              // global hist replicas (atomic contention /16)
#define CAP2    131072          // candidate cap (pool ~50k at 14-bin slack)
#define SLACK_BINS 14           // 12 (fp16 + GEMM noise) + 2 (1/8-sampling margin)
#define TIE_CAP 1024
#define LBUF    4096            // per-block candidate buffer (16 KB LDS)
#define SAMP_ITEMS (S_TOTAL / 8 / 8)   // 524288 sampled f16x8 items
#define WBLK    (CAP2 / 256)    // 512 write blocks in the fused write/scatter kernel

typedef _Float16 f16_t;
typedef __attribute__((ext_vector_type(8))) _Float16 f16x8;
typedef __attribute__((ext_vector_type(4))) float f32x4;

// ---------------- threefry2x32, JAX partitionable scheme, 32-bit path ----------------
__device__ __forceinline__ unsigned rotl32(unsigned v, int r) {
  return (v << r) | (v >> (32 - r));
}

__device__ float jax_u42(unsigned pos) {
  const unsigned ks0 = 0u, ks1 = 42u, ks2 = 0x1BD11BDAu ^ 0u ^ 42u;
  unsigned x0 = 0u  + ks0;
  unsigned x1 = pos + ks1;
#define TFR(r) { x0 += x1; x1 = rotl32(x1, (r)); x1 ^= x0; }
  TFR(13) TFR(15) TFR(26) TFR(6)   x0 += ks1; x1 += ks2 + 1u;
  TFR(17) TFR(29) TFR(16) TFR(24)  x0 += ks2; x1 += ks0 + 2u;
  TFR(13) TFR(15) TFR(26) TFR(6)   x0 += ks0; x1 += ks1 + 3u;
  TFR(17) TFR(29) TFR(16) TFR(24)  x0 += ks1; x1 += ks2 + 4u;
  TFR(13) TFR(15) TFR(26) TFR(6)   x0 += ks2; x1 += ks0 + 5u;
#undef TFR
  unsigned bits = x0 ^ x1;
  unsigned fb = (bits >> 9) | 0x3f800000u;
  float f = __uint_as_float(fb) - 1.0f;
  const float minv = 1e-6f;
  const float maxv = (float)(1.0 - 1e-6);
  float u = f * (maxv - minv) + minv;
  return fmaxf(minv, u);
}

__device__ float mask_val(float p, unsigned pos) {
  float u = jax_u42(pos);
  float l = (logf(p) - log1pf(-p) + logf(u) - log1pf(-u)) * 2.0f; // /TEMP, TEMP=0.5
  return 1.0f / (1.0f + expf(-l));
}

// f64 -> u64 monotone key (larger double <=> larger key)
__device__ __forceinline__ unsigned long long f64key(double v) {
  long long b = __double_as_longlong(v);
  return (b < 0) ? ~(unsigned long long)b
                 : ((unsigned long long)b | 0x8000000000000000ULL);
}

// ---------------- K1: per-edge counts ----------------
__global__ void count_k(const int* __restrict__ E, int* __restrict__ cnt) {
  int i = blockIdx.x * blockDim.x + threadIdx.x;
  if (i < NNZ) atomicAdd(&cnt[E[i]], 1);
}

// ---------------- K2: exclusive scan of 8192 counts ----------------
__global__ __launch_bounds__(1024) void scan_k(const int* __restrict__ cnt,
                                               int* __restrict__ offs) {
  __shared__ int part[1024];
  int t = threadIdx.x;
  int local[8]; int s = 0;
  for (int j = 0; j < 8; ++j) { local[j] = cnt[t * 8 + j]; s += local[j]; }
  part[t] = s; __syncthreads();
  int v = s;
  for (int o = 1; o < 1024; o <<= 1) {
    int add = (t >= o) ? part[t - o] : 0;
    __syncthreads();
    v += add; part[t] = v;
    __syncthreads();
  }
  int base = v - s;
  for (int j = 0; j < 8; ++j) { offs[t * 8 + j] = base; base += local[j]; }
}

// ---------------- K3: bucket scatter (CSR) ----------------
__global__ void scatter_k(const int* __restrict__ E, const int* __restrict__ offs,
                          int* __restrict__ cursor, int* __restrict__ bucket) {
  int i = blockIdx.x * blockDim.x + threadIdx.x;
  if (i < NNZ) {
    int e = E[i];
    int p = atomicAdd(&cursor[e], 1);
    bucket[offs[e] + p] = i;
  }
}

// ---------------- K4: FUSED prep — edge path (blocks < N_EDGES) + node path ----------------
// Edge: sort CSR list (ascending index == np.add.at order), f32 eX for the fp16 B
// operand AND f64 eX64 (same sorted order, same ops as the old rescore gather —
// bit-identical values, computed ONCE per edge instead of once per candidate).
// Node: fp16 A operand. B16[m][h*128+d] = eX*W^2*rnorm; A16[n][h*128+d] = X*rnorm.
__global__ __launch_bounds__(128) void prep_k(const float* __restrict__ X,
                                              const int* __restrict__ V,
                                              const int* __restrict__ cnt,
                                              const int* __restrict__ offs,
                                              const int* __restrict__ bucket,
                                              const float* __restrict__ W,
                                              f16_t* __restrict__ A16,
                                              f16_t* __restrict__ B16,
                                              double* __restrict__ eX64) {
  __shared__ int lst[512];
  __shared__ float red[2];
  int bid = blockIdx.x, t = threadIdx.x;
  int lane = t & 63, wv = t >> 6;
  if (bid < N_EDGES) {
    int m = bid;
    int deg = cnt[m], off = offs[m];
    int n = min(deg, 512);
    for (int j = t; j < n; j += 128) lst[j] = bucket[off + j];
    __syncthreads();
    if (t == 0 && n > 1) {
      for (int a = 1; a < n; ++a) {
        int key = lst[a]; int b = a - 1;
        while (b >= 0 && lst[b] > key) { lst[b + 1] = lst[b]; --b; }
        lst[b + 1] = key;
      }
    }
    __syncthreads();
    float s = 0.f;
    double s64 = 0.0;
    for (int j = 0; j < n; ++j) {
      float xv = X[(size_t)V[lst[j]] * EMB + t];
      s += xv;
      s64 += (double)xv;
    }
    float eXd = s / fmaxf((float)deg, 1.0f);
    eX64[(size_t)m * EMB + t] = s64 / fmax((double)deg, 1.0);
    for (int h = 0; h < NHEAD; ++h) {
      float wd = W[h * EMB + t];
      float val = eXd * wd;
      float ss = val * val;
      for (int o = 32; o > 0; o >>= 1) ss += __shfl_down(ss, o, 64);
      if (lane == 0) red[wv] = ss;
      __syncthreads();
      float nh = 1.0f / fmaxf(sqrtf(red[0] + red[1]), 1e-6f);
      B16[(size_t)m * (NHEAD * EMB) + h * EMB + t] = (f16_t)(eXd * wd * wd * nh);
      __syncthreads();
    }
  } else {
    int nid = bid - N_EDGES;
    float xd = X[(size_t)nid * EMB + t];
    for (int h = 0; h < NHEAD; ++h) {
      float val = xd * W[h * EMB + t];
      float ss = val * val;
      for (int o = 32; o > 0; o >>= 1) ss += __shfl_down(ss, o, 64);
      if (lane == 0) red[wv] = ss;
      __syncthreads();
      float nh = 1.0f / fmaxf(sqrtf(red[0] + red[1]), 1e-6f);
      A16[(size_t)nid * (NHEAD * EMB) + h * EMB + t] = (f16_t)(xd * nh);
      __syncthreads();
    }
  }
}

// ---------------- K5: fp16 MFMA GEMM (R1-proven loop) -> S16 via LDS-staged epilogue ----------------
// K-loop: m97 structure, 128x128 tile, 4 waves, BK=32, global_load_lds width=16,
// source-side XOR swizzle (rule #21), verified 0 bank conflicts (R2 PMC).
// Epilogue: R3 PMC showed scattered 2B C-stores cost 92 MB WRITE_SIZE for 67 MB of
// data (partial-line amplification). Stage the C-tile in LDS (stride 132: fg-groups
// 0..3 land on bank offsets {0,8,16,24} — distinct, so only the free 2-per-dword
// aliasing) and stream out 8B-aligned coalesced chunks.
__global__ __launch_bounds__(256) void gemm_k(const f16_t* __restrict__ A16,
                                              const f16_t* __restrict__ B16,
                                              unsigned short* __restrict__ S16) {
  __shared__ __align__(16) unsigned char smem[128 * 132 * 2];  // 33792 B
  f16_t* As = (f16_t*)smem;                    // 8 KB   (K-loop)
  f16_t* Bs = (f16_t*)(smem + 8192);           // 8 KB   (K-loop)
  unsigned short* Cs = (unsigned short*)smem;  // 33 KB  (epilogue, after barrier)
  const int tid  = threadIdx.x;
  const int lane = tid & 63;
  const int wv   = tid >> 6;
  const int m0   = blockIdx.x * 128;       // edge cols
  const int n0   = blockIdx.y * 128;       // node rows
  const int wr   = (wv >> 1) * 64;
  const int wc   = (wv & 1) * 64;
  const int frow = lane & 15;
  const int fg   = lane >> 4;
  const int sw   = (frow >> 1) & 3;
  const int fo   = ((fg ^ sw) << 3);

  f32x4 acc[4][4];
#pragma unroll
  for (int i = 0; i < 4; ++i)
#pragma unroll
    for (int j = 0; j < 4; ++j) acc[i][j] = (f32x4){0.f, 0.f, 0.f, 0.f};

  for (int k0 = 0; k0 < 512; k0 += 32) {
    __syncthreads();
#pragma unroll
    for (int r = 0; r < 2; ++r) {
      int chunk = r * 256 + wv * 64 + lane;
      int row   = chunk >> 2;
      int cb    = ((chunk & 3) ^ ((chunk >> 3) & 3)) << 3;
      __builtin_amdgcn_global_load_lds(
          (const __attribute__((address_space(1))) void*)
              (A16 + ((size_t)(n0 + row) << 9) + k0 + cb),
          (__attribute__((address_space(3))) void*)
              (As + (size_t)(r * 256 + wv * 64) * 8),
          16, 0, 0);
      __builtin_amdgcn_global_load_lds(
          (const __attribute__((address_space(1))) void*)
              (B16 + ((size_t)(m0 + row) << 9) + k0 + cb),
          (__attribute__((address_space(3))) void*)
              (Bs + (size_t)(r * 256 + wv * 64) * 8),
          16, 0, 0);
    }
    __syncthreads();
    f16x8 a[4], b[4];
#pragma unroll
    for (int i = 0; i < 4; ++i)
      a[i] = *(const f16x8*)(As + (wr + i * 16 + frow) * 32 + fo);
#pragma unroll
    for (int j = 0; j < 4; ++j)
      b[j] = *(const f16x8*)(Bs + (wc + j * 16 + frow) * 32 + fo);
#pragma unroll
    for (int i = 0; i < 4; ++i)
#pragma unroll
      for (int j = 0; j < 4; ++j)
        acc[i][j] = __builtin_amdgcn_mfma_f32_16x16x32_f16(a[i], b[j], acc[i][j], 0, 0, 0);
  }
  __syncthreads();   // all waves done with As/Bs before Cs overwrites them
  // C/D layout (m89-verified): col = lane&15, row = (lane>>4)*4 + q
#pragma unroll
  for (int i = 0; i < 4; ++i)
#pragma unroll
    for (int j = 0; j < 4; ++j)
#pragma unroll
      for (int q = 0; q < 4; ++q) {
        int rl = wr + i * 16 + fg * 4 + q;
        int cl = wc + j * 16 + frow;
        f16_t h = (f16_t)(acc[i][j][q] * 0.25f);
        Cs[rl * 132 + cl] = __builtin_bit_cast(unsigned short, h);
      }
  __syncthreads();
  // coalesced copy-out: 128 rows x 32 chunks of 4 cols (8 B, aligned: 264%8==0)
  for (int idx = tid; idx < 128 * 32; idx += 256) {
    int r  = idx >> 5;
    int ch = idx & 31;
    *(unsigned long long*)(S16 + (size_t)(n0 + r) * N_EDGES + m0 + ch * 4) =
        *(const unsigned long long*)(Cs + r * 132 + ch * 4);
  }
}

// ---------------- K6: mask existing incidences in S16 (fp16 -inf) ----------------
__global__ void maskset16_k(const int* __restrict__ V, const int* __restrict__ E,
                            unsigned short* __restrict__ S16) {
  int i = blockIdx.x * blockDim.x + threadIdx.x;
  if (i < NNZ) S16[(size_t)V[i] * N_EDGES + E[i]] = 0xFC00u;  // -inf
}

// ---------------- K7: 1/8-SAMPLED 8192-bin histogram over S16 ----------------
__global__ __launch_bounds__(256) void hist16_k(const f16x8* __restrict__ S8,
                                                unsigned* __restrict__ ghist) {
  __shared__ unsigned hh[NBINS];
  for (int i = threadIdx.x; i < NBINS; i += 256) hh[i] = 0;
  __syncthreads();
  const int stride = gridDim.x * blockDim.x;     // multiple of 64
  int j = blockIdx.x * blockDim.x + threadIdx.x;
#define BIN8(v)                                                              \
  _Pragma("unroll") for (int c = 0; c < 8; ++c) {                            \
    float bf = fminf(fmaxf(((float)(v)[c] + 1.0f) * 4096.0f, 0.0f),          \
                     (float)(NBINS - 1));                                    \
    atomicAdd(&hh[(int)bf], 1u);                                             \
  }
#define SIDX(jj) (((jj) >> 6) * 512 + ((jj) & 63))
  for (; j + 3 * stride < SAMP_ITEMS; j += 4 * stride) {
    f16x8 v0 = S8[SIDX(j)];
    f16x8 v1 = S8[SIDX(j + stride)];
    f16x8 v2 = S8[SIDX(j + 2 * stride)];
    f16x8 v3 = S8[SIDX(j + 3 * stride)];
    BIN8(v0) BIN8(v1) BIN8(v2) BIN8(v3)
  }
  for (; j < SAMP_ITEMS; j += stride) { f16x8 v = S8[SIDX(j)]; BIN8(v) }
#undef SIDX
#undef BIN8
  __syncthreads();
  unsigned* gh = ghist + (size_t)(blockIdx.x & (NREP - 1)) * NBINS;
  for (int i2 = threadIdx.x; i2 < NBINS; i2 += 256) {
    unsigned c = hh[i2];
    if (c) atomicAdd(&gh[i2], c);
  }
}

// ---------------- K8: screening threshold from the SAMPLED hist ----------------
__global__ __launch_bounds__(1024) void thresh_k(const unsigned* __restrict__ hist,
                                                 float* __restrict__ T_lo) {
  __shared__ int suff[1024];
  int t = threadIdx.x;
  const int G = NBINS / 1024;
  int b0 = t * G;
  int s = 0;
  for (int j = 0; j < G; ++j) {
    unsigned tb = 0;
    for (int r = 0; r < NREP; ++r) tb += hist[(size_t)r * NBINS + b0 + j];
    s += (int)tb;
  }
  int v = s;
  suff[t] = v; __syncthreads();
  for (int o = 1; o < 1024; o <<= 1) {
    int add = (t + o < 1024) ? suff[t + o] : 0;
    __syncthreads();
    v += add; suff[t] = v;
    __syncthreads();
  }
  int above = (t < 1023) ? suff[t + 1] : 0;
  if (above < K_SAMP && suff[t] >= K_SAMP) {
    int running = above;
    int B = b0;
    for (int b = b0 + G - 1; b >= b0; --b) {
      unsigned tb = 0;
      for (int r = 0; r < NREP; ++r) tb += hist[(size_t)r * NBINS + b];
      running += (int)tb;
      if (running >= K_SAMP) { B = b; break; }
    }
    B = max(B, SLACK_BINS);
    *T_lo = (float)(B - SLACK_BINS) * (1.0f / 4096.0f) - 1.0f;
  }
}

// ---------------- K9: compact candidates, two-level counter (R5-proven) ----------------
__global__ __launch_bounds__(256) void collect16_k(const f16x8* __restrict__ S8,
                                                   const float* __restrict__ T_lo_p,
                                                   unsigned* __restrict__ counter,
                                                   int* __restrict__ ci) {
  __shared__ int lbuf[LBUF];
  __shared__ unsigned lcnt, gbase;
  if (threadIdx.x == 0) lcnt = 0;
  __syncthreads();
  float T = *T_lo_p;
  const int stride = gridDim.x * blockDim.x;
  int i = blockIdx.x * blockDim.x + threadIdx.x;
#define SEL8(v, base)                                                        \
  _Pragma("unroll") for (int c = 0; c < 8; ++c) {                            \
    if ((float)(v)[c] >= T) {                                                \
      unsigned j = atomicAdd(&lcnt, 1u);                                     \
      if (j < LBUF) lbuf[j] = (base) * 8 + c;                                \
      else { unsigned g = atomicAdd(counter, 1u);                            \
             if (g < CAP2) ci[g] = (base) * 8 + c; }                         \
    }                                                                        \
  }
  for (; i + 3 * stride < S_TOTAL / 8; i += 4 * stride) {
    f16x8 v0 = S8[i];
    f16x8 v1 = S8[i + stride];
    f16x8 v2 = S8[i + 2 * stride];
    f16x8 v3 = S8[i + 3 * stride];
    SEL8(v0, i) SEL8(v1, i + stride) SEL8(v2, i + 2 * stride) SEL8(v3, i + 3 * stride)
  }
  for (; i < S_TOTAL / 8; i += stride) { f16x8 v = S8[i]; SEL8(v, i) }
#undef SEL8
  __syncthreads();
  unsigned n = min(lcnt, (unsigned)LBUF);
  if (threadIdx.x == 0) gbase = atomicAdd(counter, n);
  __syncthreads();
  unsigned gb = gbase;
  for (unsigned t = threadIdx.x; t < n; t += 256) {
    unsigned p = gb + t;
    if (p < CAP2) ci[p] = lbuf[t];
  }
}

// ---------------- K10: f64 rescore via precomputed eX64 (gather loop removed) ----------------
__global__ __launch_bounds__(256) void rescore_k(const float* __restrict__ X,
                                                 const float* __restrict__ W,
                                                 const double* __restrict__ eX64,
                                                 const int* __restrict__ ci,
                                                 const unsigned* __restrict__ counter,
                                                 unsigned long long* __restrict__ ckey) {
  int C = (int)min(*counter, (unsigned)CAP2);
  int wave = threadIdx.x >> 6, lane = threadIdx.x & 63;
  int j = blockIdx.x * 4 + wave;
  if (j >= C) return;
  int pos = ci[j];
  int n = pos >> 13;
  int m = pos & 8191;
  double e0 = eX64[(size_t)m * EMB + lane];
  double e1 = eX64[(size_t)m * EMB + lane + 64];
  const float* xr = X + (size_t)n * EMB;
  double x0 = (double)xr[lane], x1 = (double)xr[lane + 64];
  double s = 0.0;
  for (int h = 0; h < NHEAD; ++h) {
    const float* wr = W + h * EMB;
    double w0 = (double)wr[lane], w1 = (double)wr[lane + 64];
    double xw0 = x0 * w0, xw1 = x1 * w1;
    double ew0 = e0 * w0, ew1 = e1 * w1;
    double an = xw0 * xw0 + xw1 * xw1;
    double ae = ew0 * ew0 + ew1 * ew1;
    double dt = xw0 * ew0 + xw1 * ew1;
    for (int o = 32; o > 0; o >>= 1) {
      an += __shfl_down(an, o, 64);
      ae += __shfl_down(ae, o, 64);
      dt += __shfl_down(dt, o, 64);
    }
    if (lane == 0) {
      double Nn = fmax(sqrt(an), 1e-6);
      double Ne = fmax(sqrt(ae), 1e-6);
      s += dt / (Nn * Ne);
    }
  }
  if (lane == 0) ckey[j] = f64key(s * 0.25);
}

// ---------------- K11: exact k-th largest key via 8-level byte radix select ----------------
__global__ __launch_bounds__(1024) void kth_k(const unsigned long long* __restrict__ keys,
                                              const unsigned* __restrict__ counter,
                                              unsigned long long* __restrict__ thr) {
  __shared__ unsigned hist[256];
  __shared__ unsigned long long s_prefix;
  __shared__ unsigned s_kleft, s_cgreat;
  int C = (int)min(*counter, (unsigned)CAP2);
  if (threadIdx.x == 0) { s_prefix = 0ULL; s_kleft = K_TOP; s_cgreat = 0u; }
  __syncthreads();
  for (int level = 7; level >= 0; --level) {
    for (int i = threadIdx.x; i < 256; i += 1024) hist[i] = 0;
    __syncthreads();
    unsigned long long prefix = s_prefix;
    unsigned long long pmask = (level == 7) ? 0ULL : (~0ULL << ((level + 1) * 8));
    int sh = level * 8;
    int i = threadIdx.x;
    for (; i + 3 * 1024 < C; i += 4 * 1024) {        // x4 MLP (collect16 lesson)
      unsigned long long k0 = keys[i];
      unsigned long long k1 = keys[i + 1024];
      unsigned long long k2 = keys[i + 2048];
      unsigned long long k3 = keys[i + 3072];
      if ((k0 & pmask) == prefix) atomicAdd(&hist[(unsigned)((k0 >> sh) & 0xFF)], 1u);
      if ((k1 & pmask) == prefix) atomicAdd(&hist[(unsigned)((k1 >> sh) & 0xFF)], 1u);
      if ((k2 & pmask) == prefix) atomicAdd(&hist[(unsigned)((k2 >> sh) & 0xFF)], 1u);
      if ((k3 & pmask) == prefix) atomicAdd(&hist[(unsigned)((k3 >> sh) & 0xFF)], 1u);
    }
    for (; i < C; i += 1024) {
      unsigned long long k = keys[i];
      if ((k & pmask) == prefix) atomicAdd(&hist[(unsigned)((k >> sh) & 0xFF)], 1u);
    }
    __syncthreads();
    if (threadIdx.x == 0) {
      unsigned cum = 0; int b = 0;
      for (int i2 = 255; i2 >= 0; --i2) {
        if (cum + hist[i2] >= s_kleft) { b = i2; break; }
        cum += hist[i2];
      }
      s_prefix |= ((unsigned long long)b << sh);
      s_kleft  -= cum;
      s_cgreat += cum;
    }
    __syncthreads();
  }
  if (threadIdx.x == 0) { thr[0] = s_prefix; thr[1] = (unsigned long long)s_cgreat; }
}

// ---------------- K12: FUSED write (key > thr) + scatterH — disjoint positions ----------------
// blocks [0, WBLK): candidate writes (candidates are never incidences — masked -inf).
// blocks [WBLK, WBLK+NNZ/256): the (V,E) incidence positions. No overlap.
__global__ void wsH_k(const unsigned long long* __restrict__ keys,
                      const int* __restrict__ ci,
                      const unsigned* __restrict__ counter,
                      const unsigned long long* __restrict__ thr,
                      const float* __restrict__ P, float* __restrict__ out,
                      int* __restrict__ tiebuf, unsigned* __restrict__ tiecnt,
                      const int* __restrict__ V, const int* __restrict__ E) {
  int b = blockIdx.x;
  if (b < WBLK) {
    int C = (int)min(*counter, (unsigned)CAP2);
    int j = b * 256 + threadIdx.x;
    if (j >= C) return;
    unsigned long long k = keys[j];
    unsigned long long t = thr[0];
    if (k > t) {
      unsigned pos = (unsigned)ci[j];
      out[pos] = mask_val(P[pos], pos);
    } else if (k == t) {
      unsigned q = atomicAdd(tiecnt, 1u);
      if (q < TIE_CAP) tiebuf[q] = ci[j];
    }
  } else {
    int i = (b - WBLK) * 256 + threadIdx.x;
    if (i >= NNZ) return;
    unsigned pos = (unsigned)V[i] * (unsigned)N_EDGES + (unsigned)E[i];
    out[pos] = mask_val(P[pos], pos);
  }
}

// ---------------- K13: fill remaining slots from ties, ascending index ----------------
__global__ __launch_bounds__(256) void tiefin_k(const int* __restrict__ tiebuf,
                                                const unsigned* __restrict__ tiecnt,
                                                const unsigned long long* __restrict__ thr,
                                                const float* __restrict__ P,
                                                float* __restrict__ out) {
  __shared__ int idx[TIE_CAP];
  int T = (int)min(*tiecnt, (unsigned)TIE_CAP);
  int need = K_TOP - (int)thr[1];
  if (need <= 0 || T == 0) return;       // uniform exit
  for (int i = threadIdx.x; i < T; i += 256) idx[i] = tiebuf[i];
  __syncthreads();
  if (threadIdx.x == 0 && T > 1) {       // ascending flat index (top_k stable order)
    for (int a = 1; a < T; ++a) {
      int key = idx[a]; int b = a - 1;
      while (b >= 0 && idx[b] > key) { idx[b + 1] = idx[b]; --b; }
      idx[b + 1] = key;
    }
  }
  __syncthreads();
  int m = min(need, T);
  for (int i = threadIdx.x; i < m; i += 256) {
    unsigned pos = (unsigned)idx[i];
    out[pos] = mask_val(P[pos], pos);
  }
}

extern "C" void kernel_launch(void* const* d_in, const int* in_sizes, int n_in,
                              void* d_out, int out_size, void* d_ws, size_t ws_size,
                              hipStream_t stream) {
  const float* X = (const float*)d_in[0];
  // d_in[1] = H (unused: nonzeros are exactly the (V,E) pairs)
  const int*   V = (const int*)d_in[2];
  const int*   E = (const int*)d_in[3];
  const float* P = (const float*)d_in[4];
  const float* W = (const float*)d_in[5];
  float* OUT = (float*)d_out;

  // S16 (fp16 scores, 64 MB) in the upper half of d_out; full d_out memset after use.
  unsigned short* S16 = (unsigned short*)((char*)d_out + (size_t)S_TOTAL * 2);

  // ws layout (~23.4 MB). ALL zero-init regions are contiguous at the front so a
  // SINGLE memset covers them (dispatch-count reduction).
  char* w = (char*)d_ws;
  int*      cnt      = (int*)(w + 0);            // 32 KB   [zeroed]
  int*      cursor   = (int*)(w + 32768);        // 32 KB   [zeroed]
  unsigned* counter  = (unsigned*)(w + 65536);   // 4 B     [zeroed]
  float*    T_lo     = (float*)(w + 65540);      // 4 B     [zeroed]
  unsigned* tiecnt   = (unsigned*)(w + 65544);   // 4 B     [zeroed]
  unsigned long long* thr = (unsigned long long*)(w + 65552); // 16 B [zeroed]
  unsigned* ghist    = (unsigned*)(w + 65792);   // 512 KB  [zeroed] -> 590080
  int*      offs     = (int*)(w + 590080);       // 32 KB -> 622848
  int*      bucket   = (int*)(w + 622848);       // 256 KB -> 884992
  int*      cand_idx = (int*)(w + 884992);       // 512 KB -> 1409280
  unsigned long long* cand_key = (unsigned long long*)(w + 1409280); // 1 MB -> 2457856
  int*      tiebuf   = (int*)(w + 2457856);      // 4 KB -> 2461952
  f16_t*    A16      = (f16_t*)(w + 2461952);    // 4 MB -> 6656256   (16B aligned)
  f16_t*    B16      = (f16_t*)(w + 6656256);    // 8 MB -> 15044864  (16B aligned)
  double*   eX64     = (double*)(w + 15044864);  // 8 MB -> 23433472  (8B aligned)

  hipMemsetAsync(w, 0, 590080, stream);          // cnt+cursor+scalars+ghist, ONE call

  count_k     <<<NNZ / 256, 256, 0, stream>>>(E, cnt);
  scan_k      <<<1, 1024, 0, stream>>>(cnt, offs);
  scatter_k   <<<NNZ / 256, 256, 0, stream>>>(E, offs, cursor, bucket);
  prep_k      <<<N_EDGES + N_CODES, 128, 0, stream>>>(X, V, cnt, offs, bucket, W,
                                                      A16, B16, eX64);
  gemm_k      <<<dim3(N_EDGES / 128, N_CODES / 128), 256, 0, stream>>>(A16, B16, S16);
  maskset16_k <<<NNZ / 256, 256, 0, stream>>>(V, E, S16);
  hist16_k    <<<256, 256, 0, stream>>>((const f16x8*)S16, ghist);
  thresh_k    <<<1, 1024, 0, stream>>>(ghist, T_lo);
  collect16_k <<<2048, 256, 0, stream>>>((const f16x8*)S16, T_lo, counter, cand_idx);
  rescore_k   <<<CAP2 / 4, 256, 0, stream>>>(X, W, eX64, cand_idx, counter, cand_key);
  kth_k       <<<1, 1024, 0, stream>>>(cand_key, counter, thr);
  hipMemsetAsync(d_out, 0, (size_t)S_TOTAL * 4, stream);  // after S16 consumed
  wsH_k       <<<WBLK + NNZ / 256, 256, 0, stream>>>(cand_key, cand_idx, counter, thr,
                                                     P, OUT, tiebuf, tiecnt, V, E);
  tiefin_k    <<<1, 256, 0, stream>>>(tiebuf, tiecnt, thr, P, OUT);
}